// Round 2
// baseline (3500.372 us; speedup 1.0000x reference)
//
#include <hip/hip_runtime.h>
#include <hip/hip_bf16.h>
#include <math.h>

#define N_NODES 2000
#define T_STEPS 64
#define H_DIM   128
#define F_TOT   64

__device__ __forceinline__ float sigmoidf_(float x) { return 1.0f / (1.0f + expf(-x)); }
__device__ __forceinline__ float lrelu_(float x) { return x > 0.f ? x : 0.01f * x; }

// ---------------- pernode scores + wd ----------------
// pernode layout (floats): s0n@0, s0m@2048, s1n@4096, s1m@6144, wd@8192 (4)
__global__ void pernode_kernel(const float* __restrict__ st0, const float* __restrict__ w0,
                               const float* __restrict__ a0,
                               const float* __restrict__ st1, const float* __restrict__ w1,
                               const float* __restrict__ a1,
                               const float* __restrict__ Wdis, const float* __restrict__ adis,
                               float* __restrict__ pernode)
{
    int n = blockIdx.x * blockDim.x + threadIdx.x;
    if (n == 0) {
        #pragma unroll
        for (int k = 0; k < 4; ++k) {
            float s = 0.f;
            #pragma unroll
            for (int j = 0; j < 4; ++j) s += Wdis[k * 4 + j] * adis[j];
            pernode[8192 + k] = s;
        }
    }
    if (n >= N_NODES) return;
    {
        float v[8];
        #pragma unroll
        for (int d = 0; d < 8; ++d) v[d] = st0[n * 8 + d];
        float sa = 0.f, sb = 0.f;
        #pragma unroll
        for (int j = 0; j < 8; ++j) {
            float h = 0.f;
            #pragma unroll
            for (int d = 0; d < 8; ++d) h += v[d] * w0[d * 8 + j];
            sa += h * a0[j];
            sb += h * a0[8 + j];
        }
        pernode[n] = sa;
        pernode[2048 + n] = sb;
    }
    {
        float v[16];
        #pragma unroll
        for (int d = 0; d < 16; ++d) v[d] = st1[n * 16 + d];
        float sa = 0.f, sb = 0.f;
        #pragma unroll
        for (int j = 0; j < 16; ++j) {
            float h = 0.f;
            #pragma unroll
            for (int d = 0; d < 16; ++d) h += v[d] * w1[d * 16 + j];
            sa += h * a1[j];
            sb += h * a1[16 + j];
        }
        pernode[4096 + n] = sa;
        pernode[6144 + n] = sb;
    }
}

// ---------------- weight transposes for LSTM ----------------
__global__ void transpose_kernel(const float* __restrict__ Wih, const float* __restrict__ Whh,
                                 float* __restrict__ WihT, float* __restrict__ WhhT)
{
    int idx = blockIdx.x * blockDim.x + threadIdx.x;
    if (idx < 64 * 512) {
        int d = idx >> 9, j = idx & 511;
        WihT[idx] = Wih[j * 64 + d];
    }
    int idx2 = idx - 64 * 512;
    if (idx2 >= 0 && idx2 < 128 * 512) {
        int k = idx2 >> 9, j = idx2 & 511;
        WhhT[idx2] = Whh[j * 128 + k];
    }
}

// ---------------- score rows + softmax + identity ----------------
__global__ __launch_bounds__(256) void score_softmax_kernel(const float* __restrict__ dist,
                                                            const float* __restrict__ pernode,
                                                            float* __restrict__ dis)
{
    __shared__ float srow[N_NODES];
    __shared__ float red[256];
    int n = blockIdx.x;
    int tid = threadIdx.x;
    float wd0 = pernode[8192], wd1 = pernode[8193], wd2 = pernode[8194], wd3 = pernode[8195];
    float s0 = pernode[n];
    float s1 = pernode[4096 + n];
    const float* s0m = pernode + 2048;
    const float* s1m = pernode + 6144;
    float mx = -1e30f;
    for (int m = tid; m < N_NODES; m += 256) {
        float4 dv = *reinterpret_cast<const float4*>(dist + ((size_t)n * N_NODES + m) * 4);
        float sc = sigmoidf_(s0 + s0m[m]) + sigmoidf_(s1 + s1m[m])
                 + sigmoidf_(dv.x * wd0 + dv.y * wd1 + dv.z * wd2 + dv.w * wd3);
        srow[m] = sc;
        mx = fmaxf(mx, sc);
    }
    red[tid] = mx;
    __syncthreads();
    for (int off = 128; off > 0; off >>= 1) {
        if (tid < off) red[tid] = fmaxf(red[tid], red[tid + off]);
        __syncthreads();
    }
    mx = red[0];
    __syncthreads();
    float sum = 0.f;
    for (int m = tid; m < N_NODES; m += 256) {
        float e = expf(srow[m] - mx);
        srow[m] = e;
        sum += e;
    }
    red[tid] = sum;
    __syncthreads();
    for (int off = 128; off > 0; off >>= 1) {
        if (tid < off) red[tid] += red[tid + off];
        __syncthreads();
    }
    float inv = 1.f / red[0];
    for (int m = tid; m < N_NODES; m += 256) {
        float v = srow[m] * inv + (m == n ? 1.f : 0.f);  // fold identity: out = (I+dis)@h
        dis[(size_t)n * N_NODES + m] = v;
    }
}

// ---------------- per-category gating MLP ----------------
template <int D>
__device__ __forceinline__ void gate_cat(const float* __restrict__ dyn_row,
                                         const float* __restrict__ W1, const float* __restrict__ b1,
                                         const float* __restrict__ W2, const float* __restrict__ b2,
                                         float* __restrict__ xout)
{
    float v[D];
    #pragma unroll
    for (int d = 0; d < D; ++d) v[d] = dyn_row[d];
    float acc[D];
    #pragma unroll
    for (int d = 0; d < D; ++d) acc[d] = 0.f;
    for (int j = 0; j < H_DIM; ++j) {
        float hj = b1[j];
        #pragma unroll
        for (int d = 0; d < D; ++d) hj += v[d] * W1[d * H_DIM + j];
        float a = lrelu_(hj);
        #pragma unroll
        for (int d = 0; d < D; ++d) acc[d] += a * W2[j * D + d];
    }
    #pragma unroll
    for (int d = 0; d < D; ++d) xout[d] = sigmoidf_(acc[d] + b2[d]) * v[d];
}

__global__ __launch_bounds__(256) void gating_kernel(
    const float* __restrict__ dyn0, const float* __restrict__ dw1_0, const float* __restrict__ db1_0,
    const float* __restrict__ dw2_0, const float* __restrict__ db2_0,
    const float* __restrict__ dyn1, const float* __restrict__ dw1_1, const float* __restrict__ db1_1,
    const float* __restrict__ dw2_1, const float* __restrict__ db2_1,
    const float* __restrict__ dyn2, const float* __restrict__ dw1_2, const float* __restrict__ db1_2,
    const float* __restrict__ dw2_2, const float* __restrict__ db2_2,
    float* __restrict__ xout)
{
    int r = blockIdx.x * blockDim.x + threadIdx.x;
    if (r >= N_NODES * T_STEPS) return;
    float* xr = xout + (size_t)r * F_TOT;
    gate_cat<16>(dyn0 + (size_t)r * 16, dw1_0, db1_0, dw2_0, db2_0, xr);
    gate_cat<32>(dyn1 + (size_t)r * 32, dw1_1, db1_1, dw2_1, db2_1, xr + 16);
    gate_cat<16>(dyn2 + (size_t)r * 16, dw1_2, db1_2, dw2_2, db2_2, xr + 48);
}

// ---------------- LSTM: 8 samples per block, sample-parallel ----------------
__global__ __launch_bounds__(512) void lstm_kernel(const float* __restrict__ x,     // (N*T, 64)
                                                   const float* __restrict__ WihT,  // 64 x 512
                                                   const float* __restrict__ WhhT,  // 128 x 512
                                                   const float* __restrict__ bih,
                                                   const float* __restrict__ bhh,
                                                   float* __restrict__ h_all)       // (N, T, H)
{
    __shared__ float h_lds[8][H_DIM];
    __shared__ float x_lds[8][F_TOT];
    __shared__ float g_lds[8][512];
    int tid = threadIdx.x;
    int n0 = blockIdx.x * 8;
    float bsum = bih[tid] + bhh[tid];
    // thread tid owns cell state for units u = 2*tid, 2*tid+1 (same sample s)
    int s_own = tid >> 6;
    int hh0 = (tid & 63) * 2;
    float c0 = 0.f, c1 = 0.f;
    ((float*)h_lds)[2 * tid] = 0.f;
    ((float*)h_lds)[2 * tid + 1] = 0.f;
    __syncthreads();

    for (int t = 0; t < T_STEPS; ++t) {
        {
            int s = tid >> 6, d = tid & 63;
            x_lds[s][d] = x[((size_t)(n0 + s) * T_STEPS + t) * F_TOT + d];
        }
        __syncthreads();

        float acc[8];
        #pragma unroll
        for (int s = 0; s < 8; ++s) acc[s] = bsum;

        // input part: 64 features
        for (int d4 = 0; d4 < F_TOT / 4; ++d4) {
            float4 xs[8];
            #pragma unroll
            for (int s = 0; s < 8; ++s) xs[s] = *reinterpret_cast<const float4*>(&x_lds[s][d4 * 4]);
            #pragma unroll
            for (int dd = 0; dd < 4; ++dd) {
                float w = WihT[(d4 * 4 + dd) * 512 + tid];
                #pragma unroll
                for (int s = 0; s < 8; ++s) acc[s] += (&xs[s].x)[dd] * w;
            }
        }
        // recurrent part: 128 hidden
        for (int k4 = 0; k4 < H_DIM / 4; ++k4) {
            float4 hs[8];
            #pragma unroll
            for (int s = 0; s < 8; ++s) hs[s] = *reinterpret_cast<const float4*>(&h_lds[s][k4 * 4]);
            #pragma unroll
            for (int kk = 0; kk < 4; ++kk) {
                float w = WhhT[(k4 * 4 + kk) * 512 + tid];
                #pragma unroll
                for (int s = 0; s < 8; ++s) acc[s] += (&hs[s].x)[kk] * w;
            }
        }
        #pragma unroll
        for (int s = 0; s < 8; ++s) g_lds[s][tid] = acc[s];
        __syncthreads();

        // gate combine for the two owned units
        {
            float i0 = g_lds[s_own][hh0],       f0 = g_lds[s_own][128 + hh0];
            float gg0 = g_lds[s_own][256 + hh0], o0 = g_lds[s_own][384 + hh0];
            float i1 = g_lds[s_own][hh0 + 1],       f1 = g_lds[s_own][128 + hh0 + 1];
            float gg1 = g_lds[s_own][256 + hh0 + 1], o1 = g_lds[s_own][384 + hh0 + 1];
            c0 = sigmoidf_(f0) * c0 + sigmoidf_(i0) * tanhf(gg0);
            c1 = sigmoidf_(f1) * c1 + sigmoidf_(i1) * tanhf(gg1);
            float h0 = sigmoidf_(o0) * tanhf(c0);
            float h1 = sigmoidf_(o1) * tanhf(c1);
            h_lds[s_own][hh0] = h0;
            h_lds[s_own][hh0 + 1] = h1;
            size_t base = ((size_t)(n0 + s_own) * T_STEPS + t) * H_DIM + hh0;
            h_all[base] = h0;
            h_all[base + 1] = h1;
        }
        __syncthreads();
    }
}

// ---------------- spatial aggregation GEMM: C = (I+dis) @ h_all ----------------
// A: 2000x2000, B: 2000x8192, C: 2000x8192.  BM=BN=128, BK=16, 8x8 per thread.
__global__ __launch_bounds__(256) void agg_gemm_kernel(const float* __restrict__ A,
                                                       const float* __restrict__ B,
                                                       float* __restrict__ C)
{
    __shared__ float As[16][129];
    __shared__ float Bs[16][132];
    int col0 = blockIdx.x * 128;
    int row0 = blockIdx.y * 128;
    int tid = threadIdx.x;
    int tx = tid & 15, ty = tid >> 4;
    float acc[8][8] = {};
    for (int k0 = 0; k0 < N_NODES; k0 += 16) {   // 2000 = 125 * 16, exact
        #pragma unroll
        for (int i = 0; i < 8; ++i) {
            int e = tid + i * 256;
            int r = e >> 4, kk = e & 15;
            int gr = row0 + r;
            As[kk][r] = (gr < N_NODES) ? A[(size_t)gr * N_NODES + (k0 + kk)] : 0.f;
        }
        #pragma unroll
        for (int i = 0; i < 8; ++i) {
            int e = tid + i * 256;
            int c = e & 127, kk = e >> 7;
            Bs[kk][c] = B[(size_t)(k0 + kk) * 8192 + col0 + c];
        }
        __syncthreads();
        #pragma unroll
        for (int kk = 0; kk < 16; ++kk) {
            float a[8], b[8];
            #pragma unroll
            for (int i = 0; i < 8; ++i) a[i] = As[kk][ty * 8 + i];
            #pragma unroll
            for (int j = 0; j < 8; ++j) b[j] = Bs[kk][tx * 8 + j];
            #pragma unroll
            for (int i = 0; i < 8; ++i)
                #pragma unroll
                for (int j = 0; j < 8; ++j) acc[i][j] += a[i] * b[j];
        }
        __syncthreads();
    }
    #pragma unroll
    for (int i = 0; i < 8; ++i) {
        int gr = row0 + ty * 8 + i;
        if (gr < N_NODES) {
            float4 v0 = make_float4(acc[i][0], acc[i][1], acc[i][2], acc[i][3]);
            float4 v1 = make_float4(acc[i][4], acc[i][5], acc[i][6], acc[i][7]);
            *reinterpret_cast<float4*>(C + (size_t)gr * 8192 + col0 + tx * 8) = v0;
            *reinterpret_cast<float4*>(C + (size_t)gr * 8192 + col0 + tx * 8 + 4) = v1;
        }
    }
}

// ---------------- final projection ----------------
__global__ __launch_bounds__(256) void final_proj_kernel(const float* __restrict__ agg,
                                                         const float* __restrict__ Wl,
                                                         const float* __restrict__ bl,
                                                         const float* __restrict__ Wl2,
                                                         const float* __restrict__ bl2,
                                                         float* __restrict__ y)
{
    int r = blockIdx.x * blockDim.x + threadIdx.x;
    if (r >= N_NODES * T_STEPS) return;
    const float* row = agg + (size_t)r * H_DIM;
    float v[H_DIM];
    #pragma unroll
    for (int k = 0; k < H_DIM; k += 4) {
        float4 t = *reinterpret_cast<const float4*>(row + k);
        v[k] = t.x; v[k + 1] = t.y; v[k + 2] = t.z; v[k + 3] = t.w;
    }
    float acc = bl2[0];
    for (int j = 0; j < H_DIM; ++j) {
        float z = bl[j];
        #pragma unroll
        for (int k = 0; k < H_DIM; ++k) z += v[k] * Wl[k * H_DIM + j];
        acc += lrelu_(z) * Wl2[j];
    }
    y[r] = acc;
}

extern "C" void kernel_launch(void* const* d_in, const int* in_sizes, int n_in,
                              void* d_out, int out_size, void* d_ws, size_t ws_size,
                              hipStream_t stream)
{
    const float* dyn0  = (const float*)d_in[0];
    const float* dw1_0 = (const float*)d_in[1];
    const float* db1_0 = (const float*)d_in[2];
    const float* dw2_0 = (const float*)d_in[3];
    const float* db2_0 = (const float*)d_in[4];
    const float* dyn1  = (const float*)d_in[5];
    const float* dw1_1 = (const float*)d_in[6];
    const float* db1_1 = (const float*)d_in[7];
    const float* dw2_1 = (const float*)d_in[8];
    const float* db2_1 = (const float*)d_in[9];
    const float* dyn2  = (const float*)d_in[10];
    const float* dw1_2 = (const float*)d_in[11];
    const float* db1_2 = (const float*)d_in[12];
    const float* dw2_2 = (const float*)d_in[13];
    const float* db2_2 = (const float*)d_in[14];
    const float* st0   = (const float*)d_in[15];
    const float* w_0   = (const float*)d_in[16];
    const float* a_0   = (const float*)d_in[17];
    const float* st1   = (const float*)d_in[18];
    const float* w_1   = (const float*)d_in[19];
    const float* a_1   = (const float*)d_in[20];
    const float* dist  = (const float*)d_in[21];
    const float* W_dis = (const float*)d_in[22];
    const float* a_dis = (const float*)d_in[23];
    const float* Wih   = (const float*)d_in[24];
    const float* Whh   = (const float*)d_in[25];
    const float* bih   = (const float*)d_in[26];
    const float* bhh   = (const float*)d_in[27];
    const float* Wl    = (const float*)d_in[28];
    const float* bl    = (const float*)d_in[29];
    const float* Wl2   = (const float*)d_in[30];
    const float* bl2   = (const float*)d_in[31];

    float* ws = (float*)d_ws;
    float* pernode = ws;                    // 16384 floats
    float* WihT = ws + 16384;               // 32768 floats
    float* WhhT = WihT + 32768;             // 65536 floats
    float* dis  = WhhT + 65536;             // 4,000,000 floats
    float* xbuf = dis + 4000000;            // 8,192,000 floats
    float* hall = xbuf + 8192000;           // 16,384,000 floats
    float* aggb = hall + 16384000;          // 16,384,000 floats
    // total ~45.1M floats = ~180 MB of ws

    hipLaunchKernelGGL(pernode_kernel, dim3(8), dim3(256), 0, stream,
                       st0, w_0, a_0, st1, w_1, a_1, W_dis, a_dis, pernode);
    hipLaunchKernelGGL(transpose_kernel, dim3(384), dim3(256), 0, stream,
                       Wih, Whh, WihT, WhhT);
    hipLaunchKernelGGL(score_softmax_kernel, dim3(N_NODES), dim3(256), 0, stream,
                       dist, pernode, dis);
    hipLaunchKernelGGL(gating_kernel, dim3(500), dim3(256), 0, stream,
                       dyn0, dw1_0, db1_0, dw2_0, db2_0,
                       dyn1, dw1_1, db1_1, dw2_1, db2_1,
                       dyn2, dw1_2, db1_2, dw2_2, db2_2, xbuf);
    hipLaunchKernelGGL(lstm_kernel, dim3(N_NODES / 8), dim3(512), 0, stream,
                       xbuf, WihT, WhhT, bih, bhh, hall);
    hipLaunchKernelGGL(agg_gemm_kernel, dim3(8192 / 128, 16), dim3(256), 0, stream,
                       dis, hall, aggb);
    hipLaunchKernelGGL(final_proj_kernel, dim3(500), dim3(256), 0, stream,
                       aggb, Wl, bl, Wl2, bl2, (float*)d_out);
}

// Round 4
// 1739.628 us; speedup vs baseline: 2.0121x; 2.0121x over previous
//
#include <hip/hip_runtime.h>
#include <hip/hip_bf16.h>
#include <math.h>

#define N_NODES 2000
#define T_STEPS 64
#define H_DIM   128
#define F_TOT   64
#define KP      2048   // padded K (and padded M) for the MFMA GEMM
#define NCOLS   8192   // T*H

typedef unsigned short ushort_t;
typedef unsigned int uint_t;
typedef short bf16x8 __attribute__((ext_vector_type(8)));
typedef float f32x4 __attribute__((ext_vector_type(4)));

__device__ __forceinline__ float sigmoidf_(float x) { return 1.0f / (1.0f + expf(-x)); }
__device__ __forceinline__ float lrelu_(float x) { return x > 0.f ? x : 0.01f * x; }

// round-to-nearest-even f32 -> bf16 bits
__device__ __forceinline__ ushort_t f2bf(float x) {
    union { float f; uint_t u; } v; v.f = x;
    uint_t r = v.u + 0x7FFFu + ((v.u >> 16) & 1u);
    return (ushort_t)(r >> 16);
}

// async 16B/lane global->LDS (wave-uniform LDS base, HW adds lane*16)
__device__ __forceinline__ void stage16(const ushort_t* g, ushort_t* l) {
    __builtin_amdgcn_global_load_lds(
        (const __attribute__((address_space(1))) uint_t*)g,
        (__attribute__((address_space(3))) uint_t*)l,
        16, 0, 0);
}

// ---------------- pernode scores + wd ----------------
// pernode layout (floats): s0n@0, s0m@2048, s1n@4096, s1m@6144, wd@8192 (4)
__global__ void pernode_kernel(const float* __restrict__ st0, const float* __restrict__ w0,
                               const float* __restrict__ a0,
                               const float* __restrict__ st1, const float* __restrict__ w1,
                               const float* __restrict__ a1,
                               const float* __restrict__ Wdis, const float* __restrict__ adis,
                               float* __restrict__ pernode)
{
    int n = blockIdx.x * blockDim.x + threadIdx.x;
    if (n == 0) {
        #pragma unroll
        for (int k = 0; k < 4; ++k) {
            float s = 0.f;
            #pragma unroll
            for (int j = 0; j < 4; ++j) s += Wdis[k * 4 + j] * adis[j];
            pernode[8192 + k] = s;
        }
    }
    if (n >= N_NODES) return;
    {
        float v[8];
        #pragma unroll
        for (int d = 0; d < 8; ++d) v[d] = st0[n * 8 + d];
        float sa = 0.f, sb = 0.f;
        #pragma unroll
        for (int j = 0; j < 8; ++j) {
            float h = 0.f;
            #pragma unroll
            for (int d = 0; d < 8; ++d) h += v[d] * w0[d * 8 + j];
            sa += h * a0[j];
            sb += h * a0[8 + j];
        }
        pernode[n] = sa;
        pernode[2048 + n] = sb;
    }
    {
        float v[16];
        #pragma unroll
        for (int d = 0; d < 16; ++d) v[d] = st1[n * 16 + d];
        float sa = 0.f, sb = 0.f;
        #pragma unroll
        for (int j = 0; j < 16; ++j) {
            float h = 0.f;
            #pragma unroll
            for (int d = 0; d < 16; ++d) h += v[d] * w1[d * 16 + j];
            sa += h * a1[j];
            sb += h * a1[16 + j];
        }
        pernode[4096 + n] = sa;
        pernode[6144 + n] = sb;
    }
}

// ---------------- weight transposes for LSTM ----------------
__global__ void transpose_kernel(const float* __restrict__ Wih, const float* __restrict__ Whh,
                                 float* __restrict__ WihT, float* __restrict__ WhhT)
{
    int idx = blockIdx.x * blockDim.x + threadIdx.x;
    if (idx < 64 * 512) {
        int d = idx >> 9, j = idx & 511;
        WihT[idx] = Wih[j * 64 + d];
    }
    int idx2 = idx - 64 * 512;
    if (idx2 >= 0 && idx2 < 128 * 512) {
        int k = idx2 >> 9, j = idx2 & 511;
        WhhT[idx2] = Whh[j * 128 + k];
    }
}

// ---------------- score rows + softmax + identity -> bf16 A ----------------
__global__ __launch_bounds__(256) void score_softmax_kernel(const float* __restrict__ dist,
                                                            const float* __restrict__ pernode,
                                                            ushort_t* __restrict__ Abf)
{
    __shared__ float srow[N_NODES];
    __shared__ float red[256];
    int n = blockIdx.x;
    int tid = threadIdx.x;
    float wd0 = pernode[8192], wd1 = pernode[8193], wd2 = pernode[8194], wd3 = pernode[8195];
    float s0 = pernode[n];
    float s1 = pernode[4096 + n];
    const float* s0m = pernode + 2048;
    const float* s1m = pernode + 6144;
    float mx = -1e30f;
    for (int m = tid; m < N_NODES; m += 256) {
        float4 dv = *reinterpret_cast<const float4*>(dist + ((size_t)n * N_NODES + m) * 4);
        float sc = sigmoidf_(s0 + s0m[m]) + sigmoidf_(s1 + s1m[m])
                 + sigmoidf_(dv.x * wd0 + dv.y * wd1 + dv.z * wd2 + dv.w * wd3);
        srow[m] = sc;
        mx = fmaxf(mx, sc);
    }
    red[tid] = mx;
    __syncthreads();
    for (int off = 128; off > 0; off >>= 1) {
        if (tid < off) red[tid] = fmaxf(red[tid], red[tid + off]);
        __syncthreads();
    }
    mx = red[0];
    __syncthreads();
    float sum = 0.f;
    for (int m = tid; m < N_NODES; m += 256) {
        float e = expf(srow[m] - mx);
        srow[m] = e;
        sum += e;
    }
    red[tid] = sum;
    __syncthreads();
    for (int off = 128; off > 0; off >>= 1) {
        if (tid < off) red[tid] += red[tid + off];
        __syncthreads();
    }
    float inv = 1.f / red[0];
    for (int m = tid; m < KP; m += 256) {
        float v = 0.f;
        if (m < N_NODES) v = srow[m] * inv + (m == n ? 1.f : 0.f);  // fold identity
        Abf[(size_t)n * KP + m] = f2bf(v);
    }
}

// ---------------- zero pad rows 2000..2047 of A ----------------
__global__ void padA_kernel(ushort_t* __restrict__ Abf)
{
    uint_t* p = (uint_t*)(Abf + (size_t)N_NODES * KP);
    int idx = blockIdx.x * blockDim.x + threadIdx.x;   // 192*256 = 49152 = 48*2048/2
    p[idx] = 0;
}

// ---------------- per-category gating MLP ----------------
template <int D>
__device__ __forceinline__ void gate_cat(const float* __restrict__ dyn_row,
                                         const float* __restrict__ W1, const float* __restrict__ b1,
                                         const float* __restrict__ W2, const float* __restrict__ b2,
                                         float* __restrict__ xout)
{
    float v[D];
    #pragma unroll
    for (int d = 0; d < D; ++d) v[d] = dyn_row[d];
    float acc[D];
    #pragma unroll
    for (int d = 0; d < D; ++d) acc[d] = 0.f;
    for (int j = 0; j < H_DIM; ++j) {
        float hj = b1[j];
        #pragma unroll
        for (int d = 0; d < D; ++d) hj += v[d] * W1[d * H_DIM + j];
        float a = lrelu_(hj);
        #pragma unroll
        for (int d = 0; d < D; ++d) acc[d] += a * W2[j * D + d];
    }
    #pragma unroll
    for (int d = 0; d < D; ++d) xout[d] = sigmoidf_(acc[d] + b2[d]) * v[d];
}

__global__ __launch_bounds__(256) void gating_kernel(
    const float* __restrict__ dyn0, const float* __restrict__ dw1_0, const float* __restrict__ db1_0,
    const float* __restrict__ dw2_0, const float* __restrict__ db2_0,
    const float* __restrict__ dyn1, const float* __restrict__ dw1_1, const float* __restrict__ db1_1,
    const float* __restrict__ dw2_1, const float* __restrict__ db2_1,
    const float* __restrict__ dyn2, const float* __restrict__ dw1_2, const float* __restrict__ db1_2,
    const float* __restrict__ dw2_2, const float* __restrict__ db2_2,
    float* __restrict__ xout)
{
    int r = blockIdx.x * blockDim.x + threadIdx.x;
    if (r >= N_NODES * T_STEPS) return;
    float* xr = xout + (size_t)r * F_TOT;
    gate_cat<16>(dyn0 + (size_t)r * 16, dw1_0, db1_0, dw2_0, db2_0, xr);
    gate_cat<32>(dyn1 + (size_t)r * 32, dw1_1, db1_1, dw2_1, db2_1, xr + 16);
    gate_cat<16>(dyn2 + (size_t)r * 16, dw1_2, db1_2, dw2_2, db2_2, xr + 48);
}

// ---------------- LSTM: 8 samples per block, writes bf16 h ----------------
__global__ __launch_bounds__(512) void lstm_kernel(const float* __restrict__ x,     // (N*T, 64)
                                                   const float* __restrict__ WihT,  // 64 x 512
                                                   const float* __restrict__ WhhT,  // 128 x 512
                                                   const float* __restrict__ bih,
                                                   const float* __restrict__ bhh,
                                                   ushort_t* __restrict__ h_bf)     // (N, T*H) bf16
{
    __shared__ float h_lds[8][H_DIM];
    __shared__ float x_lds[8][F_TOT];
    __shared__ float g_lds[8][512];
    int tid = threadIdx.x;
    int n0 = blockIdx.x * 8;
    float bsum = bih[tid] + bhh[tid];
    int s_own = tid >> 6;
    int hh0 = (tid & 63) * 2;
    float c0 = 0.f, c1 = 0.f;
    ((float*)h_lds)[2 * tid] = 0.f;
    ((float*)h_lds)[2 * tid + 1] = 0.f;
    __syncthreads();

    for (int t = 0; t < T_STEPS; ++t) {
        {
            int s = tid >> 6, d = tid & 63;
            x_lds[s][d] = x[((size_t)(n0 + s) * T_STEPS + t) * F_TOT + d];
        }
        __syncthreads();

        float acc[8];
        #pragma unroll
        for (int s = 0; s < 8; ++s) acc[s] = bsum;

        for (int d4 = 0; d4 < F_TOT / 4; ++d4) {
            float4 xs[8];
            #pragma unroll
            for (int s = 0; s < 8; ++s) xs[s] = *reinterpret_cast<const float4*>(&x_lds[s][d4 * 4]);
            #pragma unroll
            for (int dd = 0; dd < 4; ++dd) {
                float w = WihT[(d4 * 4 + dd) * 512 + tid];
                #pragma unroll
                for (int s = 0; s < 8; ++s) acc[s] += (&xs[s].x)[dd] * w;
            }
        }
        for (int k4 = 0; k4 < H_DIM / 4; ++k4) {
            float4 hs[8];
            #pragma unroll
            for (int s = 0; s < 8; ++s) hs[s] = *reinterpret_cast<const float4*>(&h_lds[s][k4 * 4]);
            #pragma unroll
            for (int kk = 0; kk < 4; ++kk) {
                float w = WhhT[(k4 * 4 + kk) * 512 + tid];
                #pragma unroll
                for (int s = 0; s < 8; ++s) acc[s] += (&hs[s].x)[kk] * w;
            }
        }
        #pragma unroll
        for (int s = 0; s < 8; ++s) g_lds[s][tid] = acc[s];
        __syncthreads();

        {
            float i0 = g_lds[s_own][hh0],       f0 = g_lds[s_own][128 + hh0];
            float gg0 = g_lds[s_own][256 + hh0], o0 = g_lds[s_own][384 + hh0];
            float i1 = g_lds[s_own][hh0 + 1],       f1 = g_lds[s_own][128 + hh0 + 1];
            float gg1 = g_lds[s_own][256 + hh0 + 1], o1 = g_lds[s_own][384 + hh0 + 1];
            c0 = sigmoidf_(f0) * c0 + sigmoidf_(i0) * tanhf(gg0);
            c1 = sigmoidf_(f1) * c1 + sigmoidf_(i1) * tanhf(gg1);
            float h0 = sigmoidf_(o0) * tanhf(c0);
            float h1 = sigmoidf_(o1) * tanhf(c1);
            h_lds[s_own][hh0] = h0;
            h_lds[s_own][hh0 + 1] = h1;
            size_t base = ((size_t)(n0 + s_own) * T_STEPS + t) * H_DIM + hh0;
            uint_t pk = (uint_t)f2bf(h0) | ((uint_t)f2bf(h1) << 16);
            *(uint_t*)&h_bf[base] = pk;
        }
        __syncthreads();
    }
}

// ---------------- transpose h (2000 x 8192 bf16) -> hT (8192 x 2048 bf16) ----------------
__global__ __launch_bounds__(256) void transposeH_kernel(const ushort_t* __restrict__ h_bf,
                                                         ushort_t* __restrict__ hT)
{
    __shared__ ushort_t tile[64][72];
    int c0 = blockIdx.x * 64;   // column of h / row of hT   (0..8191)
    int k0 = blockIdx.y * 64;   // row (node) of h / col of hT (0..2047)
    int tid = threadIdx.x;
    int rr = tid >> 4;          // 0..15
    int cc = (tid & 15) * 4;    // 0..60
    #pragma unroll
    for (int i = 0; i < 4; ++i) {
        int r = rr + i * 16;    // 0..63
        ushort_t v0 = 0, v1 = 0, v2 = 0, v3 = 0;
        if (k0 + r < N_NODES) {
            const ushort_t* src = h_bf + (size_t)(k0 + r) * NCOLS + c0 + cc;
            ushort4 v = *reinterpret_cast<const ushort4*>(src);
            v0 = v.x; v1 = v.y; v2 = v.z; v3 = v.w;
        }
        tile[r][cc] = v0; tile[r][cc + 1] = v1; tile[r][cc + 2] = v2; tile[r][cc + 3] = v3;
    }
    __syncthreads();
    #pragma unroll
    for (int i = 0; i < 4; ++i) {
        int r = rr + i * 16;    // row of hT tile (c-dim), 0..63
        ushort4 v;
        v.x = tile[cc][r]; v.y = tile[cc + 1][r]; v.z = tile[cc + 2][r]; v.w = tile[cc + 3][r];
        *reinterpret_cast<ushort4*>(hT + (size_t)(c0 + r) * KP + k0 + cc) = v;
    }
}

// ---------------- spatial aggregation via MFMA: C = (I+dis) @ h ----------------
// A: Abf [2048 x 2048] bf16 row-major, B: hT [8192 x 2048] bf16 (col-major of h),
// C: fp32 [2000 x 8192].  m97 structure: BM=BN=128, BK=32, 4 waves, 16x16x32 MFMA.
__global__ __launch_bounds__(256) void agg_gemm_mfma(const ushort_t* __restrict__ Abf,
                                                     const ushort_t* __restrict__ hT,
                                                     float* __restrict__ C)
{
    __shared__ ushort_t A_lds[128 * 32];
    __shared__ ushort_t B_lds[128 * 32];
    int tid = threadIdx.x;
    int lane = tid & 63;
    int w = tid >> 6;          // wave 0..3
    int wr = w >> 1, wc = w & 1;
    int row0 = blockIdx.y * 128;
    int col0 = blockIdx.x * 128;

    f32x4 acc[4][4] = {};

    int lrow = lane >> 2;            // 0..15 (row-within-16 for staging)
    int lkk = (lane & 3) * 8;        // bf16 elements within 32-k row

    for (int k0 = 0; k0 < KP; k0 += 32) {
        // stage A tile: rows row0..row0+127, k k0..k0+31
        stage16(Abf + (size_t)(row0 + w * 16 + lrow) * KP + k0 + lkk,       &A_lds[w * 512]);
        stage16(Abf + (size_t)(row0 + 64 + w * 16 + lrow) * KP + k0 + lkk,  &A_lds[w * 512 + 2048]);
        // stage B tile: cols col0..col0+127 (rows of hT), same k range
        stage16(hT + (size_t)(col0 + w * 16 + lrow) * KP + k0 + lkk,        &B_lds[w * 512]);
        stage16(hT + (size_t)(col0 + 64 + w * 16 + lrow) * KP + k0 + lkk,   &B_lds[w * 512 + 2048]);
        __syncthreads();

        bf16x8 av[4], bv[4];
        #pragma unroll
        for (int mi = 0; mi < 4; ++mi)
            av[mi] = *(const bf16x8*)&A_lds[(wr * 64 + mi * 16 + (lane & 15)) * 32 + (lane >> 4) * 8];
        #pragma unroll
        for (int ni = 0; ni < 4; ++ni)
            bv[ni] = *(const bf16x8*)&B_lds[(wc * 64 + ni * 16 + (lane & 15)) * 32 + (lane >> 4) * 8];
        #pragma unroll
        for (int mi = 0; mi < 4; ++mi)
            #pragma unroll
            for (int ni = 0; ni < 4; ++ni)
                acc[mi][ni] = __builtin_amdgcn_mfma_f32_16x16x32_bf16(av[mi], bv[ni], acc[mi][ni], 0, 0, 0);
        __syncthreads();
    }

    // epilogue: D row = (lane>>4)*4 + reg, col = lane&15  [m89-verified]
    #pragma unroll
    for (int mi = 0; mi < 4; ++mi) {
        #pragma unroll
        for (int ni = 0; ni < 4; ++ni) {
            int colg = col0 + wc * 64 + ni * 16 + (lane & 15);
            #pragma unroll
            for (int j = 0; j < 4; ++j) {
                int rowg = row0 + wr * 64 + mi * 16 + (lane >> 4) * 4 + j;
                if (rowg < N_NODES)
                    C[(size_t)rowg * NCOLS + colg] = acc[mi][ni][j];
            }
        }
    }
}

// ---------------- final projection ----------------
__global__ __launch_bounds__(256) void final_proj_kernel(const float* __restrict__ agg,
                                                         const float* __restrict__ Wl,
                                                         const float* __restrict__ bl,
                                                         const float* __restrict__ Wl2,
                                                         const float* __restrict__ bl2,
                                                         float* __restrict__ y)
{
    int r = blockIdx.x * blockDim.x + threadIdx.x;
    if (r >= N_NODES * T_STEPS) return;
    const float* row = agg + (size_t)r * H_DIM;
    float v[H_DIM];
    #pragma unroll
    for (int k = 0; k < H_DIM; k += 4) {
        float4 t = *reinterpret_cast<const float4*>(row + k);
        v[k] = t.x; v[k + 1] = t.y; v[k + 2] = t.z; v[k + 3] = t.w;
    }
    float acc = bl2[0];
    for (int j = 0; j < H_DIM; ++j) {
        float z = bl[j];
        #pragma unroll
        for (int k = 0; k < H_DIM; ++k) z += v[k] * Wl[k * H_DIM + j];
        acc += lrelu_(z) * Wl2[j];
    }
    y[r] = acc;
}

extern "C" void kernel_launch(void* const* d_in, const int* in_sizes, int n_in,
                              void* d_out, int out_size, void* d_ws, size_t ws_size,
                              hipStream_t stream)
{
    const float* dyn0  = (const float*)d_in[0];
    const float* dw1_0 = (const float*)d_in[1];
    const float* db1_0 = (const float*)d_in[2];
    const float* dw2_0 = (const float*)d_in[3];
    const float* db2_0 = (const float*)d_in[4];
    const float* dyn1  = (const float*)d_in[5];
    const float* dw1_1 = (const float*)d_in[6];
    const float* db1_1 = (const float*)d_in[7];
    const float* dw2_1 = (const float*)d_in[8];
    const float* db2_1 = (const float*)d_in[9];
    const float* dyn2  = (const float*)d_in[10];
    const float* dw1_2 = (const float*)d_in[11];
    const float* db1_2 = (const float*)d_in[12];
    const float* dw2_2 = (const float*)d_in[13];
    const float* db2_2 = (const float*)d_in[14];
    const float* st0   = (const float*)d_in[15];
    const float* w_0   = (const float*)d_in[16];
    const float* a_0   = (const float*)d_in[17];
    const float* st1   = (const float*)d_in[18];
    const float* w_1   = (const float*)d_in[19];
    const float* a_1   = (const float*)d_in[20];
    const float* dist  = (const float*)d_in[21];
    const float* W_dis = (const float*)d_in[22];
    const float* a_dis = (const float*)d_in[23];
    const float* Wih   = (const float*)d_in[24];
    const float* Whh   = (const float*)d_in[25];
    const float* bih   = (const float*)d_in[26];
    const float* bhh   = (const float*)d_in[27];
    const float* Wl    = (const float*)d_in[28];
    const float* bl    = (const float*)d_in[29];
    const float* Wl2   = (const float*)d_in[30];
    const float* bl2   = (const float*)d_in[31];

    char* ws = (char*)d_ws;
    float* pernode = (float*)ws;                                   //  65,536 B
    float* WihT    = (float*)(ws + 65536);                         // 131,072 B
    float* WhhT    = (float*)(ws + 196608);                        // 262,144 B
    float* xbuf    = (float*)(ws + 458752);                        // 32,768,000 B
    float* aggb    = (float*)(ws + 33226752);                      // 65,536,000 B
    ushort_t* Abf  = (ushort_t*)(ws + 98762752);                   //  8,388,608 B (2048x2048)
    ushort_t* hbf  = (ushort_t*)(ws + 107151360);                  // 32,768,000 B (2000x8192)
    ushort_t* hT   = (ushort_t*)(ws + 139919360);                  // 33,554,432 B (8192x2048)
    // total 173,473,792 B (< previous 180 MB footprint)

    hipLaunchKernelGGL(pernode_kernel, dim3(8), dim3(256), 0, stream,
                       st0, w_0, a_0, st1, w_1, a_1, W_dis, a_dis, pernode);
    hipLaunchKernelGGL(transpose_kernel, dim3(384), dim3(256), 0, stream,
                       Wih, Whh, WihT, WhhT);
    hipLaunchKernelGGL(score_softmax_kernel, dim3(N_NODES), dim3(256), 0, stream,
                       dist, pernode, Abf);
    hipLaunchKernelGGL(padA_kernel, dim3(192), dim3(256), 0, stream, Abf);
    hipLaunchKernelGGL(gating_kernel, dim3(500), dim3(256), 0, stream,
                       dyn0, dw1_0, db1_0, dw2_0, db2_0,
                       dyn1, dw1_1, db1_1, dw2_1, db2_1,
                       dyn2, dw1_2, db1_2, dw2_2, db2_2, xbuf);
    hipLaunchKernelGGL(lstm_kernel, dim3(N_NODES / 8), dim3(512), 0, stream,
                       xbuf, WihT, WhhT, bih, bhh, hbf);
    hipLaunchKernelGGL(transposeH_kernel, dim3(NCOLS / 64, KP / 64), dim3(256), 0, stream,
                       hbf, hT);
    hipLaunchKernelGGL(agg_gemm_mfma, dim3(NCOLS / 128, KP / 128), dim3(256), 0, stream,
                       Abf, hT, aggb);
    hipLaunchKernelGGL(final_proj_kernel, dim3(500), dim3(256), 0, stream,
                       aggb, Wl, bl, Wl2, bl2, (float*)d_out);
}

// Round 5
// 885.932 us; speedup vs baseline: 3.9511x; 1.9636x over previous
//
#include <hip/hip_runtime.h>
#include <hip/hip_bf16.h>
#include <math.h>

#define N_NODES 2000
#define T_STEPS 64
#define H_DIM   128
#define F_TOT   64
#define KP      2048   // padded K (and padded M) for the agg MFMA GEMM
#define NCOLS   8192   // T*H

typedef unsigned short ushort_t;
typedef unsigned int uint_t;
typedef short bf16x8 __attribute__((ext_vector_type(8)));
typedef float f32x4 __attribute__((ext_vector_type(4)));

__device__ __forceinline__ float sigmoidf_(float x) { return 1.0f / (1.0f + expf(-x)); }
__device__ __forceinline__ float lrelu_(float x) { return x > 0.f ? x : 0.01f * x; }

// round-to-nearest-even f32 -> bf16 bits
__device__ __forceinline__ ushort_t f2bf(float x) {
    union { float f; uint_t u; } v; v.f = x;
    uint_t r = v.u + 0x7FFFu + ((v.u >> 16) & 1u);
    return (ushort_t)(r >> 16);
}

// async 16B/lane global->LDS (wave-uniform LDS base, HW adds lane*16)
__device__ __forceinline__ void stage16(const ushort_t* g, ushort_t* l) {
    __builtin_amdgcn_global_load_lds(
        (const __attribute__((address_space(1))) uint_t*)g,
        (__attribute__((address_space(3))) uint_t*)l,
        16, 0, 0);
}

// ---------------- pernode scores + wd ----------------
// pernode layout (floats): s0n@0, s0m@2048, s1n@4096, s1m@6144, wd@8192 (4)
__global__ void pernode_kernel(const float* __restrict__ st0, const float* __restrict__ w0,
                               const float* __restrict__ a0,
                               const float* __restrict__ st1, const float* __restrict__ w1,
                               const float* __restrict__ a1,
                               const float* __restrict__ Wdis, const float* __restrict__ adis,
                               float* __restrict__ pernode)
{
    int n = blockIdx.x * blockDim.x + threadIdx.x;
    if (n == 0) {
        #pragma unroll
        for (int k = 0; k < 4; ++k) {
            float s = 0.f;
            #pragma unroll
            for (int j = 0; j < 4; ++j) s += Wdis[k * 4 + j] * adis[j];
            pernode[8192 + k] = s;
        }
    }
    if (n >= N_NODES) return;
    {
        float v[8];
        #pragma unroll
        for (int d = 0; d < 8; ++d) v[d] = st0[n * 8 + d];
        float sa = 0.f, sb = 0.f;
        #pragma unroll
        for (int j = 0; j < 8; ++j) {
            float h = 0.f;
            #pragma unroll
            for (int d = 0; d < 8; ++d) h += v[d] * w0[d * 8 + j];
            sa += h * a0[j];
            sb += h * a0[8 + j];
        }
        pernode[n] = sa;
        pernode[2048 + n] = sb;
    }
    {
        float v[16];
        #pragma unroll
        for (int d = 0; d < 16; ++d) v[d] = st1[n * 16 + d];
        float sa = 0.f, sb = 0.f;
        #pragma unroll
        for (int j = 0; j < 16; ++j) {
            float h = 0.f;
            #pragma unroll
            for (int d = 0; d < 16; ++d) h += v[d] * w1[d * 16 + j];
            sa += h * a1[j];
            sb += h * a1[16 + j];
        }
        pernode[4096 + n] = sa;
        pernode[6144 + n] = sb;
    }
}

// ---------------- prep: bf16 LSTM weights ([n][k] layout = original) + bias sum ----------------
__global__ void prep_kernel(const float* __restrict__ Wih, const float* __restrict__ Whh,
                            const float* __restrict__ bih, const float* __restrict__ bhh,
                            ushort_t* __restrict__ wihbf, ushort_t* __restrict__ whhbf,
                            float* __restrict__ bsum)
{
    int idx = blockIdx.x * blockDim.x + threadIdx.x;
    if (idx < 32768) {
        wihbf[idx] = f2bf(Wih[idx]);
    } else if (idx < 98304) {
        whhbf[idx - 32768] = f2bf(Whh[idx - 32768]);
    } else if (idx < 98816) {
        bsum[idx - 98304] = bih[idx - 98304] + bhh[idx - 98304];
    }
}

// ---------------- score rows + softmax + identity -> bf16 A ----------------
__global__ __launch_bounds__(256) void score_softmax_kernel(const float* __restrict__ dist,
                                                            const float* __restrict__ pernode,
                                                            ushort_t* __restrict__ Abf)
{
    __shared__ float srow[N_NODES];
    __shared__ float red[256];
    int n = blockIdx.x;
    int tid = threadIdx.x;
    float wd0 = pernode[8192], wd1 = pernode[8193], wd2 = pernode[8194], wd3 = pernode[8195];
    float s0 = pernode[n];
    float s1 = pernode[4096 + n];
    const float* s0m = pernode + 2048;
    const float* s1m = pernode + 6144;
    float mx = -1e30f;
    for (int m = tid; m < N_NODES; m += 256) {
        float4 dv = *reinterpret_cast<const float4*>(dist + ((size_t)n * N_NODES + m) * 4);
        float sc = sigmoidf_(s0 + s0m[m]) + sigmoidf_(s1 + s1m[m])
                 + sigmoidf_(dv.x * wd0 + dv.y * wd1 + dv.z * wd2 + dv.w * wd3);
        srow[m] = sc;
        mx = fmaxf(mx, sc);
    }
    red[tid] = mx;
    __syncthreads();
    for (int off = 128; off > 0; off >>= 1) {
        if (tid < off) red[tid] = fmaxf(red[tid], red[tid + off]);
        __syncthreads();
    }
    mx = red[0];
    __syncthreads();
    float sum = 0.f;
    for (int m = tid; m < N_NODES; m += 256) {
        float e = expf(srow[m] - mx);
        srow[m] = e;
        sum += e;
    }
    red[tid] = sum;
    __syncthreads();
    for (int off = 128; off > 0; off >>= 1) {
        if (tid < off) red[tid] += red[tid + off];
        __syncthreads();
    }
    float inv = 1.f / red[0];
    for (int m = tid; m < KP; m += 256) {
        float v = 0.f;
        if (m < N_NODES) v = srow[m] * inv + (m == n ? 1.f : 0.f);  // fold identity
        Abf[(size_t)n * KP + m] = f2bf(v);
    }
}

// ---------------- zero pad rows 2000..2047 of A ----------------
__global__ void padA_kernel(ushort_t* __restrict__ Abf)
{
    uint_t* p = (uint_t*)(Abf + (size_t)N_NODES * KP);
    int idx = blockIdx.x * blockDim.x + threadIdx.x;   // 192*256 = 49152 = 48*2048/2
    p[idx] = 0;
}

// ---------------- per-category gating MLP (bf16 output) ----------------
template <int D>
__device__ __forceinline__ void gate_cat(const float* __restrict__ dyn_row,
                                         const float* __restrict__ W1, const float* __restrict__ b1,
                                         const float* __restrict__ W2, const float* __restrict__ b2,
                                         float* __restrict__ xout)
{
    float v[D];
    #pragma unroll
    for (int d = 0; d < D; ++d) v[d] = dyn_row[d];
    float acc[D];
    #pragma unroll
    for (int d = 0; d < D; ++d) acc[d] = 0.f;
    for (int j = 0; j < H_DIM; ++j) {
        float hj = b1[j];
        #pragma unroll
        for (int d = 0; d < D; ++d) hj += v[d] * W1[d * H_DIM + j];
        float a = lrelu_(hj);
        #pragma unroll
        for (int d = 0; d < D; ++d) acc[d] += a * W2[j * D + d];
    }
    #pragma unroll
    for (int d = 0; d < D; ++d) xout[d] = sigmoidf_(acc[d] + b2[d]) * v[d];
}

__global__ __launch_bounds__(256) void gating_kernel(
    const float* __restrict__ dyn0, const float* __restrict__ dw1_0, const float* __restrict__ db1_0,
    const float* __restrict__ dw2_0, const float* __restrict__ db2_0,
    const float* __restrict__ dyn1, const float* __restrict__ dw1_1, const float* __restrict__ db1_1,
    const float* __restrict__ dw2_1, const float* __restrict__ db2_1,
    const float* __restrict__ dyn2, const float* __restrict__ dw1_2, const float* __restrict__ db1_2,
    const float* __restrict__ dw2_2, const float* __restrict__ db2_2,
    ushort_t* __restrict__ xout)
{
    int r = blockIdx.x * blockDim.x + threadIdx.x;
    if (r >= N_NODES * T_STEPS) return;
    float xr[F_TOT];
    gate_cat<16>(dyn0 + (size_t)r * 16, dw1_0, db1_0, dw2_0, db2_0, xr);
    gate_cat<32>(dyn1 + (size_t)r * 32, dw1_1, db1_1, dw2_1, db2_1, xr + 16);
    gate_cat<16>(dyn2 + (size_t)r * 16, dw1_2, db1_2, dw2_2, db2_2, xr + 48);
    uint_t pk[32];
    #pragma unroll
    for (int d = 0; d < 32; ++d)
        pk[d] = (uint_t)f2bf(xr[2 * d]) | ((uint_t)f2bf(xr[2 * d + 1]) << 16);
    uint4* dst = reinterpret_cast<uint4*>(xout + (size_t)r * F_TOT);
    #pragma unroll
    for (int i = 0; i < 8; ++i)
        dst[i] = make_uint4(pk[4 * i], pk[4 * i + 1], pk[4 * i + 2], pk[4 * i + 3]);
}

// ---------------- LSTM via MFMA: 8 samples/block, 512 threads (8 waves) ----------------
// Per step: g[16(pad)x512] = x_t @ Wih^T + h @ Whh^T + b, MFMA 16x16x32.
// Wave w owns unit chunk uc=w*16 for ALL 4 gates (n = gate*128+uc+col) -> i,f,g,o
// land in the same lane's acc registers; cell update fully in-register.
// B-fragments (Wih/Whh bf16, [n][k] layout = original tensors) live in VGPRs
// across all 64 steps. A-frag LDS reads: 6 b128/wave/step (vs 384 scalar-path).
__global__ __launch_bounds__(512) void lstm_mfma_kernel(
    const ushort_t* __restrict__ xbf,   // (N*T, 64) bf16, row r = n*64+t
    const ushort_t* __restrict__ wihbf, // (512, 64) bf16  [n][k]
    const ushort_t* __restrict__ whhbf, // (512, 128) bf16 [n][k]
    const float*    __restrict__ bsum,  // (512) bih+bhh
    ushort_t*       __restrict__ h_bf)  // (N, T*H) bf16
{
    __shared__ ushort_t xb_lds[2 * 512];   // double-buffered x_t: [8 samples][64]
    __shared__ ushort_t h_lds[16 * 128];   // [16 samples(8 pad)][128] bf16

    int tid  = threadIdx.x;
    int lane = tid & 63;
    int w    = tid >> 6;          // wave 0..7
    int n0   = blockIdx.x * 8;
    int uc   = w * 16;            // unit chunk base
    int col  = lane & 15;         // C col / B n-offset
    int ke   = (lane >> 4) * 8;   // k-element base within 32-k tile
    int arow = lane & 15;         // A row for fragment reads
    int rgrp = lane >> 4;         // C rows rgrp*4+j

    // prologue: stage x[t=0] into buffer 0 (one wave, one instruction)
    if (w == 0)
        stage16(xbf + ((size_t)(n0 + (lane >> 3)) * 64 + 0) * 64 + (lane & 7) * 8,
                &xb_lds[0]);

    // zero h (h0 = 0; rows 8..15 stay zero forever)
    ((uint_t*)h_lds)[tid] = 0;
    ((uint_t*)h_lds)[512 + tid] = 0;

    // B fragments + biases (persistent across t-loop)
    bf16x8 bihf[4][2];
    bf16x8 bhhf[4][4];
    float  bias[4];
    #pragma unroll
    for (int gi = 0; gi < 4; ++gi) {
        int n = gi * 128 + uc + col;
        bias[gi] = bsum[n];
        #pragma unroll
        for (int kt = 0; kt < 2; ++kt)
            bihf[gi][kt] = *(const bf16x8*)&wihbf[n * 64 + kt * 32 + ke];
        #pragma unroll
        for (int kt = 0; kt < 4; ++kt)
            bhhf[gi][kt] = *(const bf16x8*)&whhbf[n * 128 + kt * 32 + ke];
    }

    float c_st[4] = {0.f, 0.f, 0.f, 0.f};
    __syncthreads();   // x[0] staged (vmcnt drained), h zeros visible

    for (int t = 0; t < T_STEPS; ++t) {
        // ---- A fragments ----
        const ushort_t* xb = &xb_lds[(t & 1) * 512];
        bf16x8 ax[2] = {};
        if (arow < 8) {
            ax[0] = *(const bf16x8*)&xb[arow * 64 + ke];
            ax[1] = *(const bf16x8*)&xb[arow * 64 + 32 + ke];
        }
        bf16x8 ah[4];
        #pragma unroll
        for (int kt = 0; kt < 4; ++kt)
            ah[kt] = *(const bf16x8*)&h_lds[arow * 128 + kt * 32 + ke];
        __syncthreads();   // all reads done before any h writes this step

        // prefetch next x tile (latency hides under MFMA+gates; drained at end barrier)
        if (w == 0 && t + 1 < T_STEPS)
            stage16(xbf + ((size_t)(n0 + (lane >> 3)) * 64 + (t + 1)) * 64 + (lane & 7) * 8,
                    &xb_lds[((t + 1) & 1) * 512]);

        // ---- MFMA: acc[gi] = bias + x@Wih^T + h@Whh^T ----
        f32x4 acc[4];
        #pragma unroll
        for (int gi = 0; gi < 4; ++gi)
            acc[gi] = (f32x4){bias[gi], bias[gi], bias[gi], bias[gi]};
        #pragma unroll
        for (int gi = 0; gi < 4; ++gi) {
            #pragma unroll
            for (int kt = 0; kt < 2; ++kt)
                acc[gi] = __builtin_amdgcn_mfma_f32_16x16x32_bf16(ax[kt], bihf[gi][kt], acc[gi], 0, 0, 0);
            #pragma unroll
            for (int kt = 0; kt < 4; ++kt)
                acc[gi] = __builtin_amdgcn_mfma_f32_16x16x32_bf16(ah[kt], bhhf[gi][kt], acc[gi], 0, 0, 0);
        }

        // ---- gates in-register: C row = rgrp*4+j = sample (valid < 8) ----
        if (rgrp < 2) {
            #pragma unroll
            for (int j = 0; j < 4; ++j) {
                float iv = sigmoidf_(acc[0][j]);
                float fv = sigmoidf_(acc[1][j]);
                float gv = tanhf(acc[2][j]);
                float ov = sigmoidf_(acc[3][j]);
                c_st[j] = fv * c_st[j] + iv * gv;
                float hv = ov * tanhf(c_st[j]);
                int s = rgrp * 4 + j;
                ushort_t hb = f2bf(hv);
                h_lds[s * 128 + uc + col] = hb;
                h_bf[(size_t)(n0 + s) * NCOLS + t * H_DIM + uc + col] = hb;
            }
        }
        __syncthreads();   // h writes (+ wave0 prefetch vmcnt) complete
    }
}

// ---------------- transpose h (2000 x 8192 bf16) -> hT (8192 x 2048 bf16) ----------------
__global__ __launch_bounds__(256) void transposeH_kernel(const ushort_t* __restrict__ h_bf,
                                                         ushort_t* __restrict__ hT)
{
    __shared__ ushort_t tile[64][72];
    int c0 = blockIdx.x * 64;   // column of h / row of hT   (0..8191)
    int k0 = blockIdx.y * 64;   // row (node) of h / col of hT (0..2047)
    int tid = threadIdx.x;
    int rr = tid >> 4;          // 0..15
    int cc = (tid & 15) * 4;    // 0..60
    #pragma unroll
    for (int i = 0; i < 4; ++i) {
        int r = rr + i * 16;    // 0..63
        ushort_t v0 = 0, v1 = 0, v2 = 0, v3 = 0;
        if (k0 + r < N_NODES) {
            const ushort_t* src = h_bf + (size_t)(k0 + r) * NCOLS + c0 + cc;
            ushort4 v = *reinterpret_cast<const ushort4*>(src);
            v0 = v.x; v1 = v.y; v2 = v.z; v3 = v.w;
        }
        tile[r][cc] = v0; tile[r][cc + 1] = v1; tile[r][cc + 2] = v2; tile[r][cc + 3] = v3;
    }
    __syncthreads();
    #pragma unroll
    for (int i = 0; i < 4; ++i) {
        int r = rr + i * 16;    // row of hT tile (c-dim), 0..63
        ushort4 v;
        v.x = tile[cc][r]; v.y = tile[cc + 1][r]; v.z = tile[cc + 2][r]; v.w = tile[cc + 3][r];
        *reinterpret_cast<ushort4*>(hT + (size_t)(c0 + r) * KP + k0 + cc) = v;
    }
}

// ---------------- spatial aggregation via MFMA: C = (I+dis) @ h ----------------
// A: Abf [2048 x 2048] bf16 row-major, B: hT [8192 x 2048] bf16 (col-major of h),
// C: fp32 [2000 x 8192].  m97 structure: BM=BN=128, BK=32, 4 waves, 16x16x32 MFMA.
__global__ __launch_bounds__(256) void agg_gemm_mfma(const ushort_t* __restrict__ Abf,
                                                     const ushort_t* __restrict__ hT,
                                                     float* __restrict__ C)
{
    __shared__ ushort_t A_lds[128 * 32];
    __shared__ ushort_t B_lds[128 * 32];
    int tid = threadIdx.x;
    int lane = tid & 63;
    int w = tid >> 6;          // wave 0..3
    int wr = w >> 1, wc = w & 1;
    int row0 = blockIdx.y * 128;
    int col0 = blockIdx.x * 128;

    f32x4 acc[4][4] = {};

    int lrow = lane >> 2;            // 0..15 (row-within-16 for staging)
    int lkk = (lane & 3) * 8;        // bf16 elements within 32-k row

    for (int k0 = 0; k0 < KP; k0 += 32) {
        // stage A tile: rows row0..row0+127, k k0..k0+31
        stage16(Abf + (size_t)(row0 + w * 16 + lrow) * KP + k0 + lkk,       &A_lds[w * 512]);
        stage16(Abf + (size_t)(row0 + 64 + w * 16 + lrow) * KP + k0 + lkk,  &A_lds[w * 512 + 2048]);
        // stage B tile: cols col0..col0+127 (rows of hT), same k range
        stage16(hT + (size_t)(col0 + w * 16 + lrow) * KP + k0 + lkk,        &B_lds[w * 512]);
        stage16(hT + (size_t)(col0 + 64 + w * 16 + lrow) * KP + k0 + lkk,   &B_lds[w * 512 + 2048]);
        __syncthreads();

        bf16x8 av[4], bv[4];
        #pragma unroll
        for (int mi = 0; mi < 4; ++mi)
            av[mi] = *(const bf16x8*)&A_lds[(wr * 64 + mi * 16 + (lane & 15)) * 32 + (lane >> 4) * 8];
        #pragma unroll
        for (int ni = 0; ni < 4; ++ni)
            bv[ni] = *(const bf16x8*)&B_lds[(wc * 64 + ni * 16 + (lane & 15)) * 32 + (lane >> 4) * 8];
        #pragma unroll
        for (int mi = 0; mi < 4; ++mi)
            #pragma unroll
            for (int ni = 0; ni < 4; ++ni)
                acc[mi][ni] = __builtin_amdgcn_mfma_f32_16x16x32_bf16(av[mi], bv[ni], acc[mi][ni], 0, 0, 0);
        __syncthreads();
    }

    // epilogue: D row = (lane>>4)*4 + reg, col = lane&15  [m89-verified]
    #pragma unroll
    for (int mi = 0; mi < 4; ++mi) {
        #pragma unroll
        for (int ni = 0; ni < 4; ++ni) {
            int colg = col0 + wc * 64 + ni * 16 + (lane & 15);
            #pragma unroll
            for (int j = 0; j < 4; ++j) {
                int rowg = row0 + wr * 64 + mi * 16 + (lane >> 4) * 4 + j;
                if (rowg < N_NODES)
                    C[(size_t)rowg * NCOLS + colg] = acc[mi][ni][j];
            }
        }
    }
}

// ---------------- final projection ----------------
__global__ __launch_bounds__(256) void final_proj_kernel(const float* __restrict__ agg,
                                                         const float* __restrict__ Wl,
                                                         const float* __restrict__ bl,
                                                         const float* __restrict__ Wl2,
                                                         const float* __restrict__ bl2,
                                                         float* __restrict__ y)
{
    int r = blockIdx.x * blockDim.x + threadIdx.x;
    if (r >= N_NODES * T_STEPS) return;
    const float* row = agg + (size_t)r * H_DIM;
    float v[H_DIM];
    #pragma unroll
    for (int k = 0; k < H_DIM; k += 4) {
        float4 t = *reinterpret_cast<const float4*>(row + k);
        v[k] = t.x; v[k + 1] = t.y; v[k + 2] = t.z; v[k + 3] = t.w;
    }
    float acc = bl2[0];
    for (int j = 0; j < H_DIM; ++j) {
        float z = bl[j];
        #pragma unroll
        for (int k = 0; k < H_DIM; ++k) z += v[k] * Wl[k * H_DIM + j];
        acc += lrelu_(z) * Wl2[j];
    }
    y[r] = acc;
}

extern "C" void kernel_launch(void* const* d_in, const int* in_sizes, int n_in,
                              void* d_out, int out_size, void* d_ws, size_t ws_size,
                              hipStream_t stream)
{
    const float* dyn0  = (const float*)d_in[0];
    const float* dw1_0 = (const float*)d_in[1];
    const float* db1_0 = (const float*)d_in[2];
    const float* dw2_0 = (const float*)d_in[3];
    const float* db2_0 = (const float*)d_in[4];
    const float* dyn1  = (const float*)d_in[5];
    const float* dw1_1 = (const float*)d_in[6];
    const float* db1_1 = (const float*)d_in[7];
    const float* dw2_1 = (const float*)d_in[8];
    const float* db2_1 = (const float*)d_in[9];
    const float* dyn2  = (const float*)d_in[10];
    const float* dw1_2 = (const float*)d_in[11];
    const float* db1_2 = (const float*)d_in[12];
    const float* dw2_2 = (const float*)d_in[13];
    const float* db2_2 = (const float*)d_in[14];
    const float* st0   = (const float*)d_in[15];
    const float* w_0   = (const float*)d_in[16];
    const float* a_0   = (const float*)d_in[17];
    const float* st1   = (const float*)d_in[18];
    const float* w_1   = (const float*)d_in[19];
    const float* a_1   = (const float*)d_in[20];
    const float* dist  = (const float*)d_in[21];
    const float* W_dis = (const float*)d_in[22];
    const float* a_dis = (const float*)d_in[23];
    const float* Wih   = (const float*)d_in[24];
    const float* Whh   = (const float*)d_in[25];
    const float* bih   = (const float*)d_in[26];
    const float* bhh   = (const float*)d_in[27];
    const float* Wl    = (const float*)d_in[28];
    const float* bl    = (const float*)d_in[29];
    const float* Wl2   = (const float*)d_in[30];
    const float* bl2   = (const float*)d_in[31];

    char* ws = (char*)d_ws;
    float*    pernode = (float*)ws;                      // @0         65,536 B
    float*    bsum    = (float*)(ws + 65536);            //             2,048 B
    ushort_t* wihbf   = (ushort_t*)(ws + 67584);         //            65,536 B
    ushort_t* whhbf   = (ushort_t*)(ws + 133120);        //           131,072 B
    ushort_t* Abf     = (ushort_t*)(ws + 264192);        //         8,388,608 B (2048x2048)
    ushort_t* xbf     = (ushort_t*)(ws + 8652800);       //        16,384,000 B (128000x64)
    ushort_t* hbf     = (ushort_t*)(ws + 25036800);      //        32,768,000 B (2000x8192)
    ushort_t* hT      = (ushort_t*)(ws + 57804800);      //        33,554,432 B (8192x2048)
    float*    aggb    = (float*)(ws + 91359232);         //        65,536,000 B
    // total 156,895,232 B (< 173 MB known-good footprint)

    hipLaunchKernelGGL(pernode_kernel, dim3(8), dim3(256), 0, stream,
                       st0, w_0, a_0, st1, w_1, a_1, W_dis, a_dis, pernode);
    hipLaunchKernelGGL(prep_kernel, dim3(386), dim3(256), 0, stream,
                       Wih, Whh, bih, bhh, wihbf, whhbf, bsum);
    hipLaunchKernelGGL(score_softmax_kernel, dim3(N_NODES), dim3(256), 0, stream,
                       dist, pernode, Abf);
    hipLaunchKernelGGL(padA_kernel, dim3(192), dim3(256), 0, stream, Abf);
    hipLaunchKernelGGL(gating_kernel, dim3(500), dim3(256), 0, stream,
                       dyn0, dw1_0, db1_0, dw2_0, db2_0,
                       dyn1, dw1_1, db1_1, dw2_1, db2_1,
                       dyn2, dw1_2, db1_2, dw2_2, db2_2, xbf);
    hipLaunchKernelGGL(lstm_mfma_kernel, dim3(N_NODES / 8), dim3(512), 0, stream,
                       xbf, wihbf, whhbf, bsum, hbf);
    hipLaunchKernelGGL(transposeH_kernel, dim3(NCOLS / 64, KP / 64), dim3(256), 0, stream,
                       hbf, hT);
    hipLaunchKernelGGL(agg_gemm_mfma, dim3(NCOLS / 128, KP / 128), dim3(256), 0, stream,
                       Abf, hT, aggb);
    hipLaunchKernelGGL(final_proj_kernel, dim3(500), dim3(256), 0, stream,
                       aggb, Wl, bl, Wl2, bl2, (float*)d_out);
}

// Round 6
// 645.784 us; speedup vs baseline: 5.4203x; 1.3719x over previous
//
#include <hip/hip_runtime.h>
#include <hip/hip_bf16.h>
#include <math.h>

#define N_NODES 2000
#define T_STEPS 64
#define H_DIM   128
#define F_TOT   64
#define KP      2048   // padded K (and padded M) for the agg MFMA GEMM
#define NCOLS   8192   // T*H

typedef unsigned short ushort_t;
typedef unsigned int uint_t;
typedef short bf16x8 __attribute__((ext_vector_type(8)));
typedef float f32x4 __attribute__((ext_vector_type(4)));

__device__ __forceinline__ float sigmoidf_(float x) { return 1.0f / (1.0f + expf(-x)); }
__device__ __forceinline__ float lrelu_(float x) { return x > 0.f ? x : 0.01f * x; }

// round-to-nearest-even f32 -> bf16 bits
__device__ __forceinline__ ushort_t f2bf(float x) {
    union { float f; uint_t u; } v; v.f = x;
    uint_t r = v.u + 0x7FFFu + ((v.u >> 16) & 1u);
    return (ushort_t)(r >> 16);
}

// async 16B/lane global->LDS (wave-uniform LDS base, HW adds lane*16)
__device__ __forceinline__ void stage16(const ushort_t* g, ushort_t* l) {
    __builtin_amdgcn_global_load_lds(
        (const __attribute__((address_space(1))) uint_t*)g,
        (__attribute__((address_space(3))) uint_t*)l,
        16, 0, 0);
}

// ---------------- pernode scores + wd ----------------
// pernode layout (floats): s0n@0, s0m@2048, s1n@4096, s1m@6144, wd@8192 (4)
__global__ void pernode_kernel(const float* __restrict__ st0, const float* __restrict__ w0,
                               const float* __restrict__ a0,
                               const float* __restrict__ st1, const float* __restrict__ w1,
                               const float* __restrict__ a1,
                               const float* __restrict__ Wdis, const float* __restrict__ adis,
                               float* __restrict__ pernode)
{
    int n = blockIdx.x * blockDim.x + threadIdx.x;
    if (n == 0) {
        #pragma unroll
        for (int k = 0; k < 4; ++k) {
            float s = 0.f;
            #pragma unroll
            for (int j = 0; j < 4; ++j) s += Wdis[k * 4 + j] * adis[j];
            pernode[8192 + k] = s;
        }
    }
    if (n >= N_NODES) return;
    {
        float v[8];
        #pragma unroll
        for (int d = 0; d < 8; ++d) v[d] = st0[n * 8 + d];
        float sa = 0.f, sb = 0.f;
        #pragma unroll
        for (int j = 0; j < 8; ++j) {
            float h = 0.f;
            #pragma unroll
            for (int d = 0; d < 8; ++d) h += v[d] * w0[d * 8 + j];
            sa += h * a0[j];
            sb += h * a0[8 + j];
        }
        pernode[n] = sa;
        pernode[2048 + n] = sb;
    }
    {
        float v[16];
        #pragma unroll
        for (int d = 0; d < 16; ++d) v[d] = st1[n * 16 + d];
        float sa = 0.f, sb = 0.f;
        #pragma unroll
        for (int j = 0; j < 16; ++j) {
            float h = 0.f;
            #pragma unroll
            for (int d = 0; d < 16; ++d) h += v[d] * w1[d * 16 + j];
            sa += h * a1[j];
            sb += h * a1[16 + j];
        }
        pernode[4096 + n] = sa;
        pernode[6144 + n] = sb;
    }
}

// ---------------- prep: bf16 LSTM weights + bias sum + WlT bf16 ----------------
__global__ void prep_kernel(const float* __restrict__ Wih, const float* __restrict__ Whh,
                            const float* __restrict__ bih, const float* __restrict__ bhh,
                            const float* __restrict__ Wl,
                            ushort_t* __restrict__ wihbf, ushort_t* __restrict__ whhbf,
                            float* __restrict__ bsum, ushort_t* __restrict__ wlTbf)
{
    int idx = blockIdx.x * blockDim.x + threadIdx.x;
    if (idx < 32768) {
        wihbf[idx] = f2bf(Wih[idx]);
    } else if (idx < 98304) {
        whhbf[idx - 32768] = f2bf(Whh[idx - 32768]);
    } else if (idx < 98816) {
        bsum[idx - 98304] = bih[idx - 98304] + bhh[idx - 98304];
    } else if (idx < 115200) {
        int idx2 = idx - 98816;          // 0..16383
        int j = idx2 >> 7, hh = idx2 & 127;
        wlTbf[idx2] = f2bf(Wl[hh * 128 + j]);   // WlT[j][h] = Wl[h][j]
    }
}

// ---------------- score rows + softmax + identity -> bf16 A ----------------
__global__ __launch_bounds__(256) void score_softmax_kernel(const float* __restrict__ dist,
                                                            const float* __restrict__ pernode,
                                                            ushort_t* __restrict__ Abf)
{
    __shared__ float srow[N_NODES];
    __shared__ float red[256];
    int n = blockIdx.x;
    int tid = threadIdx.x;
    float wd0 = pernode[8192], wd1 = pernode[8193], wd2 = pernode[8194], wd3 = pernode[8195];
    float s0 = pernode[n];
    float s1 = pernode[4096 + n];
    const float* s0m = pernode + 2048;
    const float* s1m = pernode + 6144;
    float mx = -1e30f;
    for (int m = tid; m < N_NODES; m += 256) {
        float4 dv = *reinterpret_cast<const float4*>(dist + ((size_t)n * N_NODES + m) * 4);
        float sc = sigmoidf_(s0 + s0m[m]) + sigmoidf_(s1 + s1m[m])
                 + sigmoidf_(dv.x * wd0 + dv.y * wd1 + dv.z * wd2 + dv.w * wd3);
        srow[m] = sc;
        mx = fmaxf(mx, sc);
    }
    red[tid] = mx;
    __syncthreads();
    for (int off = 128; off > 0; off >>= 1) {
        if (tid < off) red[tid] = fmaxf(red[tid], red[tid + off]);
        __syncthreads();
    }
    mx = red[0];
    __syncthreads();
    float sum = 0.f;
    for (int m = tid; m < N_NODES; m += 256) {
        float e = expf(srow[m] - mx);
        srow[m] = e;
        sum += e;
    }
    red[tid] = sum;
    __syncthreads();
    for (int off = 128; off > 0; off >>= 1) {
        if (tid < off) red[tid] += red[tid + off];
        __syncthreads();
    }
    float inv = 1.f / red[0];
    for (int m = tid; m < KP; m += 256) {
        float v = 0.f;
        if (m < N_NODES) v = srow[m] * inv + (m == n ? 1.f : 0.f);  // fold identity
        Abf[(size_t)n * KP + m] = f2bf(v);
    }
}

// ---------------- zero pad rows 2000..2047 of A ----------------
__global__ void padA_kernel(ushort_t* __restrict__ Abf)
{
    uint_t* p = (uint_t*)(Abf + (size_t)N_NODES * KP);
    int idx = blockIdx.x * blockDim.x + threadIdx.x;   // 192*256 = 49152 = 48*2048/2
    p[idx] = 0;
}

// ---------------- per-category gating MLP (bf16 output) ----------------
template <int D>
__device__ __forceinline__ void gate_cat(const float* __restrict__ dyn_row,
                                         const float* __restrict__ W1, const float* __restrict__ b1,
                                         const float* __restrict__ W2, const float* __restrict__ b2,
                                         float* __restrict__ xout)
{
    float v[D];
    #pragma unroll
    for (int d = 0; d < D; ++d) v[d] = dyn_row[d];
    float acc[D];
    #pragma unroll
    for (int d = 0; d < D; ++d) acc[d] = 0.f;
    for (int j = 0; j < H_DIM; ++j) {
        float hj = b1[j];
        #pragma unroll
        for (int d = 0; d < D; ++d) hj += v[d] * W1[d * H_DIM + j];
        float a = lrelu_(hj);
        #pragma unroll
        for (int d = 0; d < D; ++d) acc[d] += a * W2[j * D + d];
    }
    #pragma unroll
    for (int d = 0; d < D; ++d) xout[d] = sigmoidf_(acc[d] + b2[d]) * v[d];
}

__global__ __launch_bounds__(256) void gating_kernel(
    const float* __restrict__ dyn0, const float* __restrict__ dw1_0, const float* __restrict__ db1_0,
    const float* __restrict__ dw2_0, const float* __restrict__ db2_0,
    const float* __restrict__ dyn1, const float* __restrict__ dw1_1, const float* __restrict__ db1_1,
    const float* __restrict__ dw2_1, const float* __restrict__ db2_1,
    const float* __restrict__ dyn2, const float* __restrict__ dw1_2, const float* __restrict__ db1_2,
    const float* __restrict__ dw2_2, const float* __restrict__ db2_2,
    ushort_t* __restrict__ xout)
{
    int r = blockIdx.x * blockDim.x + threadIdx.x;
    if (r >= N_NODES * T_STEPS) return;
    float xr[F_TOT];
    gate_cat<16>(dyn0 + (size_t)r * 16, dw1_0, db1_0, dw2_0, db2_0, xr);
    gate_cat<32>(dyn1 + (size_t)r * 32, dw1_1, db1_1, dw2_1, db2_1, xr + 16);
    gate_cat<16>(dyn2 + (size_t)r * 16, dw1_2, db1_2, dw2_2, db2_2, xr + 48);
    uint_t pk[32];
    #pragma unroll
    for (int d = 0; d < 32; ++d)
        pk[d] = (uint_t)f2bf(xr[2 * d]) | ((uint_t)f2bf(xr[2 * d + 1]) << 16);
    uint4* dst = reinterpret_cast<uint4*>(xout + (size_t)r * F_TOT);
    #pragma unroll
    for (int i = 0; i < 8; ++i)
        dst[i] = make_uint4(pk[4 * i], pk[4 * i + 1], pk[4 * i + 2], pk[4 * i + 3]);
}

// ---------------- LSTM via MFMA: 8 samples/block, 512 threads (8 waves) ----------------
__global__ __launch_bounds__(512) void lstm_mfma_kernel(
    const ushort_t* __restrict__ xbf,   // (N*T, 64) bf16, row r = n*64+t
    const ushort_t* __restrict__ wihbf, // (512, 64) bf16  [n][k]
    const ushort_t* __restrict__ whhbf, // (512, 128) bf16 [n][k]
    const float*    __restrict__ bsum,  // (512) bih+bhh
    ushort_t*       __restrict__ h_bf)  // (N, T*H) bf16
{
    __shared__ ushort_t xb_lds[2 * 512];   // double-buffered x_t: [8 samples][64]
    __shared__ ushort_t h_lds[16 * 128];   // [16 samples(8 pad)][128] bf16

    int tid  = threadIdx.x;
    int lane = tid & 63;
    int w    = tid >> 6;          // wave 0..7
    int n0   = blockIdx.x * 8;
    int uc   = w * 16;            // unit chunk base
    int col  = lane & 15;         // C col / B n-offset
    int ke   = (lane >> 4) * 8;   // k-element base within 32-k tile
    int arow = lane & 15;         // A row for fragment reads
    int rgrp = lane >> 4;         // C rows rgrp*4+j

    // prologue: stage x[t=0] into buffer 0 (one wave, one instruction)
    if (w == 0)
        stage16(xbf + ((size_t)(n0 + (lane >> 3)) * 64 + 0) * 64 + (lane & 7) * 8,
                &xb_lds[0]);

    // zero h (h0 = 0; rows 8..15 stay zero forever)
    ((uint_t*)h_lds)[tid] = 0;
    ((uint_t*)h_lds)[512 + tid] = 0;

    // B fragments + biases (persistent across t-loop)
    bf16x8 bihf[4][2];
    bf16x8 bhhf[4][4];
    float  bias[4];
    #pragma unroll
    for (int gi = 0; gi < 4; ++gi) {
        int n = gi * 128 + uc + col;
        bias[gi] = bsum[n];
        #pragma unroll
        for (int kt = 0; kt < 2; ++kt)
            bihf[gi][kt] = *(const bf16x8*)&wihbf[n * 64 + kt * 32 + ke];
        #pragma unroll
        for (int kt = 0; kt < 4; ++kt)
            bhhf[gi][kt] = *(const bf16x8*)&whhbf[n * 128 + kt * 32 + ke];
    }

    float c_st[4] = {0.f, 0.f, 0.f, 0.f};
    __syncthreads();   // x[0] staged (vmcnt drained), h zeros visible

    for (int t = 0; t < T_STEPS; ++t) {
        // ---- A fragments ----
        const ushort_t* xb = &xb_lds[(t & 1) * 512];
        bf16x8 ax[2] = {};
        if (arow < 8) {
            ax[0] = *(const bf16x8*)&xb[arow * 64 + ke];
            ax[1] = *(const bf16x8*)&xb[arow * 64 + 32 + ke];
        }
        bf16x8 ah[4];
        #pragma unroll
        for (int kt = 0; kt < 4; ++kt)
            ah[kt] = *(const bf16x8*)&h_lds[arow * 128 + kt * 32 + ke];
        __syncthreads();   // all reads done before any h writes this step

        // prefetch next x tile (latency hides under MFMA+gates; drained at end barrier)
        if (w == 0 && t + 1 < T_STEPS)
            stage16(xbf + ((size_t)(n0 + (lane >> 3)) * 64 + (t + 1)) * 64 + (lane & 7) * 8,
                    &xb_lds[((t + 1) & 1) * 512]);

        // ---- MFMA: acc[gi] = bias + x@Wih^T + h@Whh^T ----
        f32x4 acc[4];
        #pragma unroll
        for (int gi = 0; gi < 4; ++gi)
            acc[gi] = (f32x4){bias[gi], bias[gi], bias[gi], bias[gi]};
        #pragma unroll
        for (int gi = 0; gi < 4; ++gi) {
            #pragma unroll
            for (int kt = 0; kt < 2; ++kt)
                acc[gi] = __builtin_amdgcn_mfma_f32_16x16x32_bf16(ax[kt], bihf[gi][kt], acc[gi], 0, 0, 0);
            #pragma unroll
            for (int kt = 0; kt < 4; ++kt)
                acc[gi] = __builtin_amdgcn_mfma_f32_16x16x32_bf16(ah[kt], bhhf[gi][kt], acc[gi], 0, 0, 0);
        }

        // ---- gates in-register: C row = rgrp*4+j = sample (valid < 8) ----
        if (rgrp < 2) {
            #pragma unroll
            for (int j = 0; j < 4; ++j) {
                float iv = sigmoidf_(acc[0][j]);
                float fv = sigmoidf_(acc[1][j]);
                float gv = tanhf(acc[2][j]);
                float ov = sigmoidf_(acc[3][j]);
                c_st[j] = fv * c_st[j] + iv * gv;
                float hv = ov * tanhf(c_st[j]);
                int s = rgrp * 4 + j;
                ushort_t hb = f2bf(hv);
                h_lds[s * 128 + uc + col] = hb;
                h_bf[(size_t)(n0 + s) * NCOLS + t * H_DIM + uc + col] = hb;
            }
        }
        __syncthreads();   // h writes (+ wave0 prefetch vmcnt) complete
    }
}

// ---------------- transpose h (2000 x 8192 bf16) -> hT (8192 x 2048 bf16) ----------------
__global__ __launch_bounds__(256) void transposeH_kernel(const ushort_t* __restrict__ h_bf,
                                                         ushort_t* __restrict__ hT)
{
    __shared__ ushort_t tile[64][72];
    int c0 = blockIdx.x * 64;   // column of h / row of hT   (0..8191)
    int k0 = blockIdx.y * 64;   // row (node) of h / col of hT (0..2047)
    int tid = threadIdx.x;
    int rr = tid >> 4;          // 0..15
    int cc = (tid & 15) * 4;    // 0..60
    #pragma unroll
    for (int i = 0; i < 4; ++i) {
        int r = rr + i * 16;    // 0..63
        ushort_t v0 = 0, v1 = 0, v2 = 0, v3 = 0;
        if (k0 + r < N_NODES) {
            const ushort_t* src = h_bf + (size_t)(k0 + r) * NCOLS + c0 + cc;
            ushort4 v = *reinterpret_cast<const ushort4*>(src);
            v0 = v.x; v1 = v.y; v2 = v.z; v3 = v.w;
        }
        tile[r][cc] = v0; tile[r][cc + 1] = v1; tile[r][cc + 2] = v2; tile[r][cc + 3] = v3;
    }
    __syncthreads();
    #pragma unroll
    for (int i = 0; i < 4; ++i) {
        int r = rr + i * 16;    // row of hT tile (c-dim), 0..63
        ushort4 v;
        v.x = tile[cc][r]; v.y = tile[cc + 1][r]; v.z = tile[cc + 2][r]; v.w = tile[cc + 3][r];
        *reinterpret_cast<ushort4*>(hT + (size_t)(c0 + r) * KP + k0 + cc) = v;
    }
}

// ---------------- spatial aggregation via MFMA: C = (I+dis) @ h -> bf16 ----------------
// A: Abf [2048 x 2048] bf16 row-major, B: hT [8192 x 2048] bf16 (col-major of h),
// C: bf16 [2000 x 8192].  m97 structure: BM=BN=128, BK=32, 4 waves, 16x16x32 MFMA.
__global__ __launch_bounds__(256) void agg_gemm_mfma(const ushort_t* __restrict__ Abf,
                                                     const ushort_t* __restrict__ hT,
                                                     ushort_t* __restrict__ Cbf)
{
    __shared__ ushort_t A_lds[128 * 32];
    __shared__ ushort_t B_lds[128 * 32];
    int tid = threadIdx.x;
    int lane = tid & 63;
    int w = tid >> 6;          // wave 0..3
    int wr = w >> 1, wc = w & 1;
    int row0 = blockIdx.y * 128;
    int col0 = blockIdx.x * 128;

    f32x4 acc[4][4] = {};

    int lrow = lane >> 2;            // 0..15 (row-within-16 for staging)
    int lkk = (lane & 3) * 8;        // bf16 elements within 32-k row

    for (int k0 = 0; k0 < KP; k0 += 32) {
        // stage A tile: rows row0..row0+127, k k0..k0+31
        stage16(Abf + (size_t)(row0 + w * 16 + lrow) * KP + k0 + lkk,       &A_lds[w * 512]);
        stage16(Abf + (size_t)(row0 + 64 + w * 16 + lrow) * KP + k0 + lkk,  &A_lds[w * 512 + 2048]);
        // stage B tile: cols col0..col0+127 (rows of hT), same k range
        stage16(hT + (size_t)(col0 + w * 16 + lrow) * KP + k0 + lkk,        &B_lds[w * 512]);
        stage16(hT + (size_t)(col0 + 64 + w * 16 + lrow) * KP + k0 + lkk,   &B_lds[w * 512 + 2048]);
        __syncthreads();

        bf16x8 av[4], bv[4];
        #pragma unroll
        for (int mi = 0; mi < 4; ++mi)
            av[mi] = *(const bf16x8*)&A_lds[(wr * 64 + mi * 16 + (lane & 15)) * 32 + (lane >> 4) * 8];
        #pragma unroll
        for (int ni = 0; ni < 4; ++ni)
            bv[ni] = *(const bf16x8*)&B_lds[(wc * 64 + ni * 16 + (lane & 15)) * 32 + (lane >> 4) * 8];
        #pragma unroll
        for (int mi = 0; mi < 4; ++mi)
            #pragma unroll
            for (int ni = 0; ni < 4; ++ni)
                acc[mi][ni] = __builtin_amdgcn_mfma_f32_16x16x32_bf16(av[mi], bv[ni], acc[mi][ni], 0, 0, 0);
        __syncthreads();
    }

    // epilogue: D row = (lane>>4)*4 + reg, col = lane&15  [m89-verified]; emit bf16
    #pragma unroll
    for (int mi = 0; mi < 4; ++mi) {
        #pragma unroll
        for (int ni = 0; ni < 4; ++ni) {
            int colg = col0 + wc * 64 + ni * 16 + (lane & 15);
            #pragma unroll
            for (int j = 0; j < 4; ++j) {
                int rowg = row0 + wr * 64 + mi * 16 + (lane >> 4) * 4 + j;
                if (rowg < N_NODES)
                    Cbf[(size_t)rowg * NCOLS + colg] = f2bf(acc[mi][ni][j]);
            }
        }
    }
}

// ---------------- final projection via MFMA (operand-swapped, no LDS) ----------------
// Z^T[j][r] = sum_h WlT[j][h] * agg[r][h];  y[r] = sum_j lrelu(Z[j]+bl[j])*Wl2[j] + bl2
// Block: 256 thr / 4 waves; wave handles 32 agg rows (2 N-tiles); M = j = 8 tiles; K = h = 4 tiles.
__global__ __launch_bounds__(256) void final_proj_mfma(
    const ushort_t* __restrict__ aggbf,  // (128000, 128) bf16
    const ushort_t* __restrict__ wlTbf,  // (128, 128) bf16  [j][h]
    const float* __restrict__ bl,        // (128)
    const float* __restrict__ Wl2,       // (128)
    const float* __restrict__ bl2,       // (1)
    float* __restrict__ y)               // (128000)
{
    int tid  = threadIdx.x;
    int lane = tid & 63;
    int w    = tid >> 6;                    // 0..3
    int row0 = blockIdx.x * 128 + w * 32;   // this wave's 32 agg rows
    int col  = lane & 15;
    int rgrp = lane >> 4;                   // 0..3
    int ke   = rgrp * 8;

    // B fragments: agg rows (N dim), 2 n-tiles x 4 k-tiles, direct from global
    bf16x8 bfr[2][4];
    #pragma unroll
    for (int nt = 0; nt < 2; ++nt) {
        const ushort_t* base = aggbf + (size_t)(row0 + nt * 16 + col) * H_DIM;
        #pragma unroll
        for (int kt = 0; kt < 4; ++kt)
            bfr[nt][kt] = *(const bf16x8*)&base[kt * 32 + ke];
    }

    float yp0 = 0.f, yp1 = 0.f;
    #pragma unroll
    for (int mi = 0; mi < 8; ++mi) {
        bf16x8 af[4];
        const ushort_t* abase = wlTbf + (size_t)(mi * 16 + col) * H_DIM;
        #pragma unroll
        for (int kt = 0; kt < 4; ++kt)
            af[kt] = *(const bf16x8*)&abase[kt * 32 + ke];
        float4 blv = *reinterpret_cast<const float4*>(&bl[mi * 16 + rgrp * 4]);
        float4 w2v = *reinterpret_cast<const float4*>(&Wl2[mi * 16 + rgrp * 4]);
        f32x4 acc0 = {blv.x, blv.y, blv.z, blv.w};
        f32x4 acc1 = acc0;
        #pragma unroll
        for (int kt = 0; kt < 4; ++kt) {
            acc0 = __builtin_amdgcn_mfma_f32_16x16x32_bf16(af[kt], bfr[0][kt], acc0, 0, 0, 0);
            acc1 = __builtin_amdgcn_mfma_f32_16x16x32_bf16(af[kt], bfr[1][kt], acc1, 0, 0, 0);
        }
        yp0 += lrelu_(acc0[0]) * w2v.x + lrelu_(acc0[1]) * w2v.y
             + lrelu_(acc0[2]) * w2v.z + lrelu_(acc0[3]) * w2v.w;
        yp1 += lrelu_(acc1[0]) * w2v.x + lrelu_(acc1[1]) * w2v.y
             + lrelu_(acc1[2]) * w2v.z + lrelu_(acc1[3]) * w2v.w;
    }
    // reduce over the 4 rgrp groups (j-rows): lanes differing in bits 4,5
    yp0 += __shfl_xor(yp0, 16); yp0 += __shfl_xor(yp0, 32);
    yp1 += __shfl_xor(yp1, 16); yp1 += __shfl_xor(yp1, 32);
    if (lane < 16) {
        float b2 = bl2[0];
        y[row0 + col] = yp0 + b2;
        y[row0 + 16 + col] = yp1 + b2;
    }
}

extern "C" void kernel_launch(void* const* d_in, const int* in_sizes, int n_in,
                              void* d_out, int out_size, void* d_ws, size_t ws_size,
                              hipStream_t stream)
{
    const float* dyn0  = (const float*)d_in[0];
    const float* dw1_0 = (const float*)d_in[1];
    const float* db1_0 = (const float*)d_in[2];
    const float* dw2_0 = (const float*)d_in[3];
    const float* db2_0 = (const float*)d_in[4];
    const float* dyn1  = (const float*)d_in[5];
    const float* dw1_1 = (const float*)d_in[6];
    const float* db1_1 = (const float*)d_in[7];
    const float* dw2_1 = (const float*)d_in[8];
    const float* db2_1 = (const float*)d_in[9];
    const float* dyn2  = (const float*)d_in[10];
    const float* dw1_2 = (const float*)d_in[11];
    const float* db1_2 = (const float*)d_in[12];
    const float* dw2_2 = (const float*)d_in[13];
    const float* db2_2 = (const float*)d_in[14];
    const float* st0   = (const float*)d_in[15];
    const float* w_0   = (const float*)d_in[16];
    const float* a_0   = (const float*)d_in[17];
    const float* st1   = (const float*)d_in[18];
    const float* w_1   = (const float*)d_in[19];
    const float* a_1   = (const float*)d_in[20];
    const float* dist  = (const float*)d_in[21];
    const float* W_dis = (const float*)d_in[22];
    const float* a_dis = (const float*)d_in[23];
    const float* Wih   = (const float*)d_in[24];
    const float* Whh   = (const float*)d_in[25];
    const float* bih   = (const float*)d_in[26];
    const float* bhh   = (const float*)d_in[27];
    const float* Wl    = (const float*)d_in[28];
    const float* bl    = (const float*)d_in[29];
    const float* Wl2   = (const float*)d_in[30];
    const float* bl2   = (const float*)d_in[31];

    char* ws = (char*)d_ws;
    float*    pernode = (float*)ws;                      // @0          65,536 B
    float*    bsum    = (float*)(ws + 65536);            //              2,048 B
    ushort_t* wihbf   = (ushort_t*)(ws + 67584);         //             65,536 B
    ushort_t* whhbf   = (ushort_t*)(ws + 133120);        //            131,072 B
    ushort_t* wlTbf   = (ushort_t*)(ws + 264192);        //             32,768 B
    ushort_t* Abf     = (ushort_t*)(ws + 296960);        //          8,388,608 B (2048x2048)
    ushort_t* xbf     = (ushort_t*)(ws + 8685568);       //         16,384,000 B (128000x64)
    ushort_t* hbf     = (ushort_t*)(ws + 25069568);      //         32,768,000 B (2000x8192)
    ushort_t* hT      = (ushort_t*)(ws + 57837568);      //         33,554,432 B (8192x2048)
    ushort_t* aggbf   = (ushort_t*)(ws + 91392000);      //         32,768,000 B (128000x128)
    // total 124,160,000 B

    hipLaunchKernelGGL(pernode_kernel, dim3(8), dim3(256), 0, stream,
                       st0, w_0, a_0, st1, w_1, a_1, W_dis, a_dis, pernode);
    hipLaunchKernelGGL(prep_kernel, dim3(450), dim3(256), 0, stream,
                       Wih, Whh, bih, bhh, Wl, wihbf, whhbf, bsum, wlTbf);
    hipLaunchKernelGGL(score_softmax_kernel, dim3(N_NODES), dim3(256), 0, stream,
                       dist, pernode, Abf);
    hipLaunchKernelGGL(padA_kernel, dim3(192), dim3(256), 0, stream, Abf);
    hipLaunchKernelGGL(gating_kernel, dim3(500), dim3(256), 0, stream,
                       dyn0, dw1_0, db1_0, dw2_0, db2_0,
                       dyn1, dw1_1, db1_1, dw2_1, db2_1,
                       dyn2, dw1_2, db1_2, dw2_2, db2_2, xbf);
    hipLaunchKernelGGL(lstm_mfma_kernel, dim3(N_NODES / 8), dim3(512), 0, stream,
                       xbf, wihbf, whhbf, bsum, hbf);
    hipLaunchKernelGGL(transposeH_kernel, dim3(NCOLS / 64, KP / 64), dim3(256), 0, stream,
                       hbf, hT);
    hipLaunchKernelGGL(agg_gemm_mfma, dim3(NCOLS / 128, KP / 128), dim3(256), 0, stream,
                       Abf, hT, aggbf);
    hipLaunchKernelGGL(final_proj_mfma, dim3(1000), dim3(256), 0, stream,
                       aggbf, wlTbf, bl, Wl2, bl2, (float*)d_out);
}

// Round 8
// 608.988 us; speedup vs baseline: 5.7478x; 1.0604x over previous
//
#include <hip/hip_runtime.h>
#include <hip/hip_bf16.h>
#include <math.h>

#define N_NODES 2000
#define T_STEPS 64
#define H_DIM   128
#define F_TOT   64
#define KP      2048   // padded K (and padded M) for the agg MFMA GEMM
#define NCOLS   8192   // T*H

typedef unsigned short ushort_t;
typedef unsigned int uint_t;
typedef short bf16x8 __attribute__((ext_vector_type(8)));
typedef float f32x4 __attribute__((ext_vector_type(4)));

__device__ __forceinline__ float sigmoidf_(float x) { return 1.0f / (1.0f + expf(-x)); }
__device__ __forceinline__ float lrelu_(float x) { return x > 0.f ? x : 0.01f * x; }

// fast HW-native gate math: exp2 maps to v_exp_f32.  err ~1e-6, far below the
// bf16 noise floor (2e-3) already accepted in this pipeline.
__device__ __forceinline__ float fast_sig(float x) {
    float e = __builtin_exp2f(x * -1.44269504f);
    return 1.0f / (1.0f + e);
}
__device__ __forceinline__ float fast_tanh(float x) {
    float e = __builtin_exp2f(x * -2.88539008f);
    return 2.0f / (1.0f + e) - 1.0f;
}

// round-to-nearest-even f32 -> bf16 bits
__device__ __forceinline__ ushort_t f2bf(float x) {
    union { float f; uint_t u; } v; v.f = x;
    uint_t r = v.u + 0x7FFFu + ((v.u >> 16) & 1u);
    return (ushort_t)(r >> 16);
}

// async 16B/lane global->LDS (wave-uniform LDS base, HW adds lane*16)
__device__ __forceinline__ void stage16(const ushort_t* g, ushort_t* l) {
    __builtin_amdgcn_global_load_lds(
        (const __attribute__((address_space(1))) uint_t*)g,
        (__attribute__((address_space(3))) uint_t*)l,
        16, 0, 0);
}

// ---------------- pernode scores + wd ----------------
// pernode layout (floats): s0n@0, s0m@2048, s1n@4096, s1m@6144, wd@8192 (4)
__global__ void pernode_kernel(const float* __restrict__ st0, const float* __restrict__ w0,
                               const float* __restrict__ a0,
                               const float* __restrict__ st1, const float* __restrict__ w1,
                               const float* __restrict__ a1,
                               const float* __restrict__ Wdis, const float* __restrict__ adis,
                               float* __restrict__ pernode)
{
    int n = blockIdx.x * blockDim.x + threadIdx.x;
    if (n == 0) {
        #pragma unroll
        for (int k = 0; k < 4; ++k) {
            float s = 0.f;
            #pragma unroll
            for (int j = 0; j < 4; ++j) s += Wdis[k * 4 + j] * adis[j];
            pernode[8192 + k] = s;
        }
    }
    if (n >= N_NODES) return;
    {
        float v[8];
        #pragma unroll
        for (int d = 0; d < 8; ++d) v[d] = st0[n * 8 + d];
        float sa = 0.f, sb = 0.f;
        #pragma unroll
        for (int j = 0; j < 8; ++j) {
            float h = 0.f;
            #pragma unroll
            for (int d = 0; d < 8; ++d) h += v[d] * w0[d * 8 + j];
            sa += h * a0[j];
            sb += h * a0[8 + j];
        }
        pernode[n] = sa;
        pernode[2048 + n] = sb;
    }
    {
        float v[16];
        #pragma unroll
        for (int d = 0; d < 16; ++d) v[d] = st1[n * 16 + d];
        float sa = 0.f, sb = 0.f;
        #pragma unroll
        for (int j = 0; j < 16; ++j) {
            float h = 0.f;
            #pragma unroll
            for (int d = 0; d < 16; ++d) h += v[d] * w1[d * 16 + j];
            sa += h * a1[j];
            sb += h * a1[16 + j];
        }
        pernode[4096 + n] = sa;
        pernode[6144 + n] = sb;
    }
}

// ---------------- prep: bf16 LSTM weights + bias sum + WlT bf16 ----------------
__global__ void prep_kernel(const float* __restrict__ Wih, const float* __restrict__ Whh,
                            const float* __restrict__ bih, const float* __restrict__ bhh,
                            const float* __restrict__ Wl,
                            ushort_t* __restrict__ wihbf, ushort_t* __restrict__ whhbf,
                            float* __restrict__ bsum, ushort_t* __restrict__ wlTbf)
{
    int idx = blockIdx.x * blockDim.x + threadIdx.x;
    if (idx < 32768) {
        wihbf[idx] = f2bf(Wih[idx]);
    } else if (idx < 98304) {
        whhbf[idx - 32768] = f2bf(Whh[idx - 32768]);
    } else if (idx < 98816) {
        bsum[idx - 98304] = bih[idx - 98304] + bhh[idx - 98304];
    } else if (idx < 115200) {
        int idx2 = idx - 98816;          // 0..16383
        int j = idx2 >> 7, hh = idx2 & 127;
        wlTbf[idx2] = f2bf(Wl[hh * 128 + j]);   // WlT[j][h] = Wl[h][j]
    }
}

// ---------------- score rows + softmax + identity -> bf16 A ----------------
__global__ __launch_bounds__(256) void score_softmax_kernel(const float* __restrict__ dist,
                                                            const float* __restrict__ pernode,
                                                            ushort_t* __restrict__ Abf)
{
    __shared__ float srow[N_NODES];
    __shared__ float red[256];
    int n = blockIdx.x;
    int tid = threadIdx.x;
    float wd0 = pernode[8192], wd1 = pernode[8193], wd2 = pernode[8194], wd3 = pernode[8195];
    float s0 = pernode[n];
    float s1 = pernode[4096 + n];
    const float* s0m = pernode + 2048;
    const float* s1m = pernode + 6144;
    float mx = -1e30f;
    for (int m = tid; m < N_NODES; m += 256) {
        float4 dv = *reinterpret_cast<const float4*>(dist + ((size_t)n * N_NODES + m) * 4);
        float sc = sigmoidf_(s0 + s0m[m]) + sigmoidf_(s1 + s1m[m])
                 + sigmoidf_(dv.x * wd0 + dv.y * wd1 + dv.z * wd2 + dv.w * wd3);
        srow[m] = sc;
        mx = fmaxf(mx, sc);
    }
    red[tid] = mx;
    __syncthreads();
    for (int off = 128; off > 0; off >>= 1) {
        if (tid < off) red[tid] = fmaxf(red[tid], red[tid + off]);
        __syncthreads();
    }
    mx = red[0];
    __syncthreads();
    float sum = 0.f;
    for (int m = tid; m < N_NODES; m += 256) {
        float e = expf(srow[m] - mx);
        srow[m] = e;
        sum += e;
    }
    red[tid] = sum;
    __syncthreads();
    for (int off = 128; off > 0; off >>= 1) {
        if (tid < off) red[tid] += red[tid + off];
        __syncthreads();
    }
    float inv = 1.f / red[0];
    for (int m = tid; m < KP; m += 256) {
        float v = 0.f;
        if (m < N_NODES) v = srow[m] * inv + (m == n ? 1.f : 0.f);  // fold identity
        Abf[(size_t)n * KP + m] = f2bf(v);
    }
}

// ---------------- zero pad rows 2000..2047 of A ----------------
__global__ void padA_kernel(ushort_t* __restrict__ Abf)
{
    uint_t* p = (uint_t*)(Abf + (size_t)N_NODES * KP);
    int idx = blockIdx.x * blockDim.x + threadIdx.x;   // 192*256 = 49152 = 48*2048/2
    p[idx] = 0;
}

// ---------------- per-category gating MLP (bf16 output) ----------------
template <int D>
__device__ __forceinline__ void gate_cat(const float* __restrict__ dyn_row,
                                         const float* __restrict__ W1, const float* __restrict__ b1,
                                         const float* __restrict__ W2, const float* __restrict__ b2,
                                         float* __restrict__ xout)
{
    float v[D];
    #pragma unroll
    for (int d = 0; d < D; ++d) v[d] = dyn_row[d];
    float acc[D];
    #pragma unroll
    for (int d = 0; d < D; ++d) acc[d] = 0.f;
    for (int j = 0; j < H_DIM; ++j) {
        float hj = b1[j];
        #pragma unroll
        for (int d = 0; d < D; ++d) hj += v[d] * W1[d * H_DIM + j];
        float a = lrelu_(hj);
        #pragma unroll
        for (int d = 0; d < D; ++d) acc[d] += a * W2[j * D + d];
    }
    #pragma unroll
    for (int d = 0; d < D; ++d) xout[d] = sigmoidf_(acc[d] + b2[d]) * v[d];
}

__global__ __launch_bounds__(256) void gating_kernel(
    const float* __restrict__ dyn0, const float* __restrict__ dw1_0, const float* __restrict__ db1_0,
    const float* __restrict__ dw2_0, const float* __restrict__ db2_0,
    const float* __restrict__ dyn1, const float* __restrict__ dw1_1, const float* __restrict__ db1_1,
    const float* __restrict__ dw2_1, const float* __restrict__ db2_1,
    const float* __restrict__ dyn2, const float* __restrict__ dw1_2, const float* __restrict__ db1_2,
    const float* __restrict__ dw2_2, const float* __restrict__ db2_2,
    ushort_t* __restrict__ xout)
{
    int r = blockIdx.x * blockDim.x + threadIdx.x;
    if (r >= N_NODES * T_STEPS) return;
    float xr[F_TOT];
    gate_cat<16>(dyn0 + (size_t)r * 16, dw1_0, db1_0, dw2_0, db2_0, xr);
    gate_cat<32>(dyn1 + (size_t)r * 32, dw1_1, db1_1, dw2_1, db2_1, xr + 16);
    gate_cat<16>(dyn2 + (size_t)r * 16, dw1_2, db1_2, dw2_2, db2_2, xr + 48);
    uint_t pk[32];
    #pragma unroll
    for (int d = 0; d < 32; ++d)
        pk[d] = (uint_t)f2bf(xr[2 * d]) | ((uint_t)f2bf(xr[2 * d + 1]) << 16);
    uint4* dst = reinterpret_cast<uint4*>(xout + (size_t)r * F_TOT);
    #pragma unroll
    for (int i = 0; i < 8; ++i)
        dst[i] = make_uint4(pk[4 * i], pk[4 * i + 1], pk[4 * i + 2], pk[4 * i + 3]);
}

// ---------------- LSTM via MFMA: 8 samples/block, 512 threads (8 waves) ----------------
// Round-8: r5's PROVEN two-barrier step structure, changing only:
//  (1) h_lds XOR swizzle (both sides, plain ds ops): chunk ^= (row&7) kills the
//      16-way conflict of the 256B row stride (G4).
//  (2) x tile swizzled via pre-swizzled GLOBAL source (m173; LDS dest linear).
//  (3) fast_sig/fast_tanh (v_exp_f32 + div) replace libm expf/tanhf.
__global__ __launch_bounds__(512) void lstm_mfma_kernel(
    const ushort_t* __restrict__ xbf,   // (N*T, 64) bf16, row r = n*64+t
    const ushort_t* __restrict__ wihbf, // (512, 64) bf16  [n][k]
    const ushort_t* __restrict__ whhbf, // (512, 128) bf16 [n][k]
    const float*    __restrict__ bsum,  // (512) bih+bhh
    ushort_t*       __restrict__ h_bf)  // (N, T*H) bf16
{
    __shared__ ushort_t xb_lds[2 * 512];   // double-buffered x_t: [8 samples][64], chunk-swizzled
    __shared__ ushort_t h_lds[16 * 128];   // [16 rows(8 pad)][128] bf16, chunk-swizzled

    int tid  = threadIdx.x;
    int lane = tid & 63;
    int w    = tid >> 6;          // wave 0..7
    int n0   = blockIdx.x * 8;
    int uc   = w * 16;            // unit chunk base
    int col  = lane & 15;         // C col / B n-offset
    int ke   = (lane >> 4) * 8;   // k-element base within 32-k tile
    int arow = lane & 15;         // A row for fragment reads
    int rgrp = lane >> 4;         // 0..3; C rows rgrp*4+j

    // prologue: stage x[t=0] into buffer 0. Global chunk pre-swizzled by sample
    // so LDS slot (s,c) holds logical chunk c^s (LDS dest stays linear).
    if (w == 0) {
        int s = lane >> 3, c = lane & 7;
        stage16(xbf + ((size_t)(n0 + s) * 64 + 0) * 64 + ((c ^ s) * 8), &xb_lds[0]);
    }

    // zero h (h0 = 0; rows 8..15 stay zero forever)
    ((uint_t*)h_lds)[tid] = 0;
    ((uint_t*)h_lds)[512 + tid] = 0;

    // B fragments + biases (persistent across t-loop)
    bf16x8 bihf[4][2];
    bf16x8 bhhf[4][4];
    float  bias[4];
    #pragma unroll
    for (int gi = 0; gi < 4; ++gi) {
        int n = gi * 128 + uc + col;
        bias[gi] = bsum[n];
        #pragma unroll
        for (int kt = 0; kt < 2; ++kt)
            bihf[gi][kt] = *(const bf16x8*)&wihbf[n * 64 + kt * 32 + ke];
        #pragma unroll
        for (int kt = 0; kt < 4; ++kt)
            bhhf[gi][kt] = *(const bf16x8*)&whhbf[n * 128 + kt * 32 + ke];
    }

    float c_st[4] = {0.f, 0.f, 0.f, 0.f};
    __syncthreads();   // x[0] staged (vmcnt drained), h zeros visible

    for (int t = 0; t < T_STEPS; ++t) {
        // ---- A fragments (swizzled reads) ----
        const ushort_t* xb = &xb_lds[(t & 1) * 512];
        bf16x8 ax[2] = {};
        if (arow < 8) {
            ax[0] = *(const bf16x8*)&xb[arow * 64 + ((rgrp ^ arow) << 3)];
            ax[1] = *(const bf16x8*)&xb[arow * 64 + (((4 + rgrp) ^ arow) << 3)];
        }
        bf16x8 ah[4];
        #pragma unroll
        for (int kt = 0; kt < 4; ++kt)
            ah[kt] = *(const bf16x8*)&h_lds[arow * 128 + (((kt * 4 + rgrp) ^ (arow & 7)) << 3)];
        __syncthreads();   // all reads done before any h writes this step

        // prefetch next x tile (latency hides under MFMA+gates; drained at end barrier)
        if (w == 0 && t + 1 < T_STEPS) {
            int s = lane >> 3, c = lane & 7;
            stage16(xbf + ((size_t)(n0 + s) * 64 + (t + 1)) * 64 + ((c ^ s) * 8),
                    &xb_lds[((t + 1) & 1) * 512]);
        }

        // ---- MFMA: acc[gi] = bias + x@Wih^T + h@Whh^T ----
        f32x4 acc[4];
        #pragma unroll
        for (int gi = 0; gi < 4; ++gi)
            acc[gi] = (f32x4){bias[gi], bias[gi], bias[gi], bias[gi]};
        #pragma unroll
        for (int gi = 0; gi < 4; ++gi) {
            #pragma unroll
            for (int kt = 0; kt < 2; ++kt)
                acc[gi] = __builtin_amdgcn_mfma_f32_16x16x32_bf16(ax[kt], bihf[gi][kt], acc[gi], 0, 0, 0);
            #pragma unroll
            for (int kt = 0; kt < 4; ++kt)
                acc[gi] = __builtin_amdgcn_mfma_f32_16x16x32_bf16(ah[kt], bhhf[gi][kt], acc[gi], 0, 0, 0);
        }

        // ---- gates in-register: C row = rgrp*4+j = sample (valid < 8) ----
        if (rgrp < 2) {
            int u = uc + col;
            int uch = u >> 3, ulo = u & 7;
            #pragma unroll
            for (int j = 0; j < 4; ++j) {
                float iv = fast_sig(acc[0][j]);
                float fv = fast_sig(acc[1][j]);
                float gv = fast_tanh(acc[2][j]);
                float ov = fast_sig(acc[3][j]);
                c_st[j] = fv * c_st[j] + iv * gv;
                float hv = ov * fast_tanh(c_st[j]);
                int s = rgrp * 4 + j;
                ushort_t hbv = f2bf(hv);
                h_lds[s * 128 + ((uch ^ s) << 3) + ulo] = hbv;
                h_bf[(size_t)(n0 + s) * NCOLS + t * H_DIM + u] = hbv;
            }
        }
        __syncthreads();   // h writes (+ wave0 prefetch vmcnt) complete
    }
}

// ---------------- transpose h (2000 x 8192 bf16) -> hT (8192 x 2048 bf16) ----------------
__global__ __launch_bounds__(256) void transposeH_kernel(const ushort_t* __restrict__ h_bf,
                                                         ushort_t* __restrict__ hT)
{
    __shared__ ushort_t tile[64][72];
    int c0 = blockIdx.x * 64;   // column of h / row of hT   (0..8191)
    int k0 = blockIdx.y * 64;   // row (node) of h / col of hT (0..2047)
    int tid = threadIdx.x;
    int rr = tid >> 4;          // 0..15
    int cc = (tid & 15) * 4;    // 0..60
    #pragma unroll
    for (int i = 0; i < 4; ++i) {
        int r = rr + i * 16;    // 0..63
        ushort_t v0 = 0, v1 = 0, v2 = 0, v3 = 0;
        if (k0 + r < N_NODES) {
            const ushort_t* src = h_bf + (size_t)(k0 + r) * NCOLS + c0 + cc;
            ushort4 v = *reinterpret_cast<const ushort4*>(src);
            v0 = v.x; v1 = v.y; v2 = v.z; v3 = v.w;
        }
        tile[r][cc] = v0; tile[r][cc + 1] = v1; tile[r][cc + 2] = v2; tile[r][cc + 3] = v3;
    }
    __syncthreads();
    #pragma unroll
    for (int i = 0; i < 4; ++i) {
        int r = rr + i * 16;    // row of hT tile (c-dim), 0..63
        ushort4 v;
        v.x = tile[cc][r]; v.y = tile[cc + 1][r]; v.z = tile[cc + 2][r]; v.w = tile[cc + 3][r];
        *reinterpret_cast<ushort4*>(hT + (size_t)(c0 + r) * KP + k0 + cc) = v;
    }
}

// ---------------- spatial aggregation via MFMA: C = (I+dis) @ h -> bf16 ----------------
// A: Abf [2048 x 2048] bf16 row-major, B: hT [8192 x 2048] bf16 (col-major of h),
// C: bf16 [2000 x 8192].  m97 structure: BM=BN=128, BK=32, 4 waves, 16x16x32 MFMA.
__global__ __launch_bounds__(256) void agg_gemm_mfma(const ushort_t* __restrict__ Abf,
                                                     const ushort_t* __restrict__ hT,
                                                     ushort_t* __restrict__ Cbf)
{
    __shared__ ushort_t A_lds[128 * 32];
    __shared__ ushort_t B_lds[128 * 32];
    int tid = threadIdx.x;
    int lane = tid & 63;
    int w = tid >> 6;          // wave 0..3
    int wr = w >> 1, wc = w & 1;
    int row0 = blockIdx.y * 128;
    int col0 = blockIdx.x * 128;

    f32x4 acc[4][4] = {};

    int lrow = lane >> 2;            // 0..15 (row-within-16 for staging)
    int lkk = (lane & 3) * 8;        // bf16 elements within 32-k row

    for (int k0 = 0; k0 < KP; k0 += 32) {
        // stage A tile: rows row0..row0+127, k k0..k0+31
        stage16(Abf + (size_t)(row0 + w * 16 + lrow) * KP + k0 + lkk,       &A_lds[w * 512]);
        stage16(Abf + (size_t)(row0 + 64 + w * 16 + lrow) * KP + k0 + lkk,  &A_lds[w * 512 + 2048]);
        // stage B tile: cols col0..col0+127 (rows of hT), same k range
        stage16(hT + (size_t)(col0 + w * 16 + lrow) * KP + k0 + lkk,        &B_lds[w * 512]);
        stage16(hT + (size_t)(col0 + 64 + w * 16 + lrow) * KP + k0 + lkk,   &B_lds[w * 512 + 2048]);
        __syncthreads();

        bf16x8 av[4], bv[4];
        #pragma unroll
        for (int mi = 0; mi < 4; ++mi)
            av[mi] = *(const bf16x8*)&A_lds[(wr * 64 + mi * 16 + (lane & 15)) * 32 + (lane >> 4) * 8];
        #pragma unroll
        for (int ni = 0; ni < 4; ++ni)
            bv[ni] = *(const bf16x8*)&B_lds[(wc * 64 + ni * 16 + (lane & 15)) * 32 + (lane >> 4) * 8];
        #pragma unroll
        for (int mi = 0; mi < 4; ++mi)
            #pragma unroll
            for (int ni = 0; ni < 4; ++ni)
                acc[mi][ni] = __builtin_amdgcn_mfma_f32_16x16x32_bf16(av[mi], bv[ni], acc[mi][ni], 0, 0, 0);
        __syncthreads();
    }

    // epilogue: D row = (lane>>4)*4 + reg, col = lane&15  [m89-verified]; emit bf16
    #pragma unroll
    for (int mi = 0; mi < 4; ++mi) {
        #pragma unroll
        for (int ni = 0; ni < 4; ++ni) {
            int colg = col0 + wc * 64 + ni * 16 + (lane & 15);
            #pragma unroll
            for (int j = 0; j < 4; ++j) {
                int rowg = row0 + wr * 64 + mi * 16 + (lane >> 4) * 4 + j;
                if (rowg < N_NODES)
                    Cbf[(size_t)rowg * NCOLS + colg] = f2bf(acc[mi][ni][j]);
            }
        }
    }
}

// ---------------- final projection via MFMA (operand-swapped, no LDS) ----------------
// Z^T[j][r] = sum_h WlT[j][h] * agg[r][h];  y[r] = sum_j lrelu(Z[j]+bl[j])*Wl2[j] + bl2
// Block: 256 thr / 4 waves; wave handles 32 agg rows (2 N-tiles); M = j = 8 tiles; K = h = 4 tiles.
__global__ __launch_bounds__(256) void final_proj_mfma(
    const ushort_t* __restrict__ aggbf,  // (128000, 128) bf16
    const ushort_t* __restrict__ wlTbf,  // (128, 128) bf16  [j][h]
    const float* __restrict__ bl,        // (128)
    const float* __restrict__ Wl2,       // (128)
    const float* __restrict__ bl2,       // (1)
    float* __restrict__ y)               // (128000)
{
    int tid  = threadIdx.x;
    int lane = tid & 63;
    int w    = tid >> 6;                    // 0..3
    int row0 = blockIdx.x * 128 + w * 32;   // this wave's 32 agg rows
    int col  = lane & 15;
    int rgrp = lane >> 4;                   // 0..3
    int ke   = rgrp * 8;

    // B fragments: agg rows (N dim), 2 n-tiles x 4 k-tiles, direct from global
    bf16x8 bfr[2][4];
    #pragma unroll
    for (int nt = 0; nt < 2; ++nt) {
        const ushort_t* base = aggbf + (size_t)(row0 + nt * 16 + col) * H_DIM;
        #pragma unroll
        for (int kt = 0; kt < 4; ++kt)
            bfr[nt][kt] = *(const bf16x8*)&base[kt * 32 + ke];
    }

    float yp0 = 0.f, yp1 = 0.f;
    #pragma unroll
    for (int mi = 0; mi < 8; ++mi) {
        bf16x8 af[4];
        const ushort_t* abase = wlTbf + (size_t)(mi * 16 + col) * H_DIM;
        #pragma unroll
        for (int kt = 0; kt < 4; ++kt)
            af[kt] = *(const bf16x8*)&abase[kt * 32 + ke];
        float4 blv = *reinterpret_cast<const float4*>(&bl[mi * 16 + rgrp * 4]);
        float4 w2v = *reinterpret_cast<const float4*>(&Wl2[mi * 16 + rgrp * 4]);
        f32x4 acc0 = {blv.x, blv.y, blv.z, blv.w};
        f32x4 acc1 = acc0;
        #pragma unroll
        for (int kt = 0; kt < 4; ++kt) {
            acc0 = __builtin_amdgcn_mfma_f32_16x16x32_bf16(af[kt], bfr[0][kt], acc0, 0, 0, 0);
            acc1 = __builtin_amdgcn_mfma_f32_16x16x32_bf16(af[kt], bfr[1][kt], acc1, 0, 0, 0);
        }
        yp0 += lrelu_(acc0[0]) * w2v.x + lrelu_(acc0[1]) * w2v.y
             + lrelu_(acc0[2]) * w2v.z + lrelu_(acc0[3]) * w2v.w;
        yp1 += lrelu_(acc1[0]) * w2v.x + lrelu_(acc1[1]) * w2v.y
             + lrelu_(acc1[2]) * w2v.z + lrelu_(acc1[3]) * w2v.w;
    }
    // reduce over the 4 rgrp groups (j-rows): lanes differing in bits 4,5
    yp0 += __shfl_xor(yp0, 16); yp0 += __shfl_xor(yp0, 32);
    yp1 += __shfl_xor(yp1, 16); yp1 += __shfl_xor(yp1, 32);
    if (lane < 16) {
        float b2 = bl2[0];
        y[row0 + col] = yp0 + b2;
        y[row0 + 16 + col] = yp1 + b2;
    }
}

extern "C" void kernel_launch(void* const* d_in, const int* in_sizes, int n_in,
                              void* d_out, int out_size, void* d_ws, size_t ws_size,
                              hipStream_t stream)
{
    const float* dyn0  = (const float*)d_in[0];
    const float* dw1_0 = (const float*)d_in[1];
    const float* db1_0 = (const float*)d_in[2];
    const float* dw2_0 = (const float*)d_in[3];
    const float* db2_0 = (const float*)d_in[4];
    const float* dyn1  = (const float*)d_in[5];
    const float* dw1_1 = (const float*)d_in[6];
    const float* db1_1 = (const float*)d_in[7];
    const float* dw2_1 = (const float*)d_in[8];
    const float* db2_1 = (const float*)d_in[9];
    const float* dyn2  = (const float*)d_in[10];
    const float* dw1_2 = (const float*)d_in[11];
    const float* db1_2 = (const float*)d_in[12];
    const float* dw2_2 = (const float*)d_in[13];
    const float* db2_2 = (const float*)d_in[14];
    const float* st0   = (const float*)d_in[15];
    const float* w_0   = (const float*)d_in[16];
    const float* a_0   = (const float*)d_in[17];
    const float* st1   = (const float*)d_in[18];
    const float* w_1   = (const float*)d_in[19];
    const float* a_1   = (const float*)d_in[20];
    const float* dist  = (const float*)d_in[21];
    const float* W_dis = (const float*)d_in[22];
    const float* a_dis = (const float*)d_in[23];
    const float* Wih   = (const float*)d_in[24];
    const float* Whh   = (const float*)d_in[25];
    const float* bih   = (const float*)d_in[26];
    const float* bhh   = (const float*)d_in[27];
    const float* Wl    = (const float*)d_in[28];
    const float* bl    = (const float*)d_in[29];
    const float* Wl2   = (const float*)d_in[30];
    const float* bl2   = (const float*)d_in[31];

    char* ws = (char*)d_ws;
    float*    pernode = (float*)ws;                      // @0          65,536 B
    float*    bsum    = (float*)(ws + 65536);            //              2,048 B
    ushort_t* wihbf   = (ushort_t*)(ws + 67584);         //             65,536 B
    ushort_t* whhbf   = (ushort_t*)(ws + 133120);        //            131,072 B
    ushort_t* wlTbf   = (ushort_t*)(ws + 264192);        //             32,768 B
    ushort_t* Abf     = (ushort_t*)(ws + 296960);        //          8,388,608 B (2048x2048)
    ushort_t* xbf     = (ushort_t*)(ws + 8685568);       //         16,384,000 B (128000x64)
    ushort_t* hbf     = (ushort_t*)(ws + 25069568);      //         32,768,000 B (2000x8192)
    ushort_t* hT      = (ushort_t*)(ws + 57837568);      //         33,554,432 B (8192x2048)
    ushort_t* aggbf   = (ushort_t*)(ws + 91392000);      //         32,768,000 B (128000x128)
    // total 124,160,000 B

    hipLaunchKernelGGL(pernode_kernel, dim3(8), dim3(256), 0, stream,
                       st0, w_0, a_0, st1, w_1, a_1, W_dis, a_dis, pernode);
    hipLaunchKernelGGL(prep_kernel, dim3(450), dim3(256), 0, stream,
                       Wih, Whh, bih, bhh, Wl, wihbf, whhbf, bsum, wlTbf);
    hipLaunchKernelGGL(score_softmax_kernel, dim3(N_NODES), dim3(256), 0, stream,
                       dist, pernode, Abf);
    hipLaunchKernelGGL(padA_kernel, dim3(192), dim3(256), 0, stream, Abf);
    hipLaunchKernelGGL(gating_kernel, dim3(500), dim3(256), 0, stream,
                       dyn0, dw1_0, db1_0, dw2_0, db2_0,
                       dyn1, dw1_1, db1_1, dw2_1, db2_1,
                       dyn2, dw1_2, db1_2, dw2_2, db2_2, xbf);
    hipLaunchKernelGGL(lstm_mfma_kernel, dim3(N_NODES / 8), dim3(512), 0, stream,
                       xbf, wihbf, whhbf, bsum, hbf);
    hipLaunchKernelGGL(transposeH_kernel, dim3(NCOLS / 64, KP / 64), dim3(256), 0, stream,
                       hbf, hT);
    hipLaunchKernelGGL(agg_gemm_mfma, dim3(NCOLS / 128, KP / 128), dim3(256), 0, stream,
                       Abf, hT, aggbf);
    hipLaunchKernelGGL(final_proj_mfma, dim3(1000), dim3(256), 0, stream,
                       aggbf, wlTbf, bl, Wl2, bl2, (float*)d_out);
}

// Round 9
// 515.738 us; speedup vs baseline: 6.7871x; 1.1808x over previous
//
#include <hip/hip_runtime.h>
#include <hip/hip_bf16.h>
#include <math.h>

#define N_NODES 2000
#define T_STEPS 64
#define H_DIM   128
#define F_TOT   64
#define KP      2048   // padded K (and padded M) for the agg MFMA GEMM
#define NCOLS   8192   // T*H

typedef unsigned short ushort_t;
typedef unsigned int uint_t;
typedef short bf16x8 __attribute__((ext_vector_type(8)));
typedef float f32x4 __attribute__((ext_vector_type(4)));

__device__ __forceinline__ float sigmoidf_(float x) { return 1.0f / (1.0f + expf(-x)); }
__device__ __forceinline__ float lrelu_(float x) { return x > 0.f ? x : 0.01f * x; }

// fast HW-native gate math: exp2 maps to v_exp_f32.  err ~1e-6, far below the
// bf16 noise floor (2e-3) already accepted in this pipeline.
__device__ __forceinline__ float fast_sig(float x) {
    float e = __builtin_exp2f(x * -1.44269504f);
    return 1.0f / (1.0f + e);
}
__device__ __forceinline__ float fast_tanh(float x) {
    float e = __builtin_exp2f(x * -2.88539008f);
    return 2.0f / (1.0f + e) - 1.0f;
}

// round-to-nearest-even f32 -> bf16 bits
__device__ __forceinline__ ushort_t f2bf(float x) {
    union { float f; uint_t u; } v; v.f = x;
    uint_t r = v.u + 0x7FFFu + ((v.u >> 16) & 1u);
    return (ushort_t)(r >> 16);
}

// async 16B/lane global->LDS (wave-uniform LDS base, HW adds lane*16)
__device__ __forceinline__ void stage16(const ushort_t* g, ushort_t* l) {
    __builtin_amdgcn_global_load_lds(
        (const __attribute__((address_space(1))) uint_t*)g,
        (__attribute__((address_space(3))) uint_t*)l,
        16, 0, 0);
}

// ---------------- pernode scores + wd ----------------
// pernode layout (floats): s0n@0, s0m@2048, s1n@4096, s1m@6144, wd@8192 (4)
__global__ void pernode_kernel(const float* __restrict__ st0, const float* __restrict__ w0,
                               const float* __restrict__ a0,
                               const float* __restrict__ st1, const float* __restrict__ w1,
                               const float* __restrict__ a1,
                               const float* __restrict__ Wdis, const float* __restrict__ adis,
                               float* __restrict__ pernode)
{
    int n = blockIdx.x * blockDim.x + threadIdx.x;
    if (n == 0) {
        #pragma unroll
        for (int k = 0; k < 4; ++k) {
            float s = 0.f;
            #pragma unroll
            for (int j = 0; j < 4; ++j) s += Wdis[k * 4 + j] * adis[j];
            pernode[8192 + k] = s;
        }
    }
    if (n >= N_NODES) return;
    {
        float v[8];
        #pragma unroll
        for (int d = 0; d < 8; ++d) v[d] = st0[n * 8 + d];
        float sa = 0.f, sb = 0.f;
        #pragma unroll
        for (int j = 0; j < 8; ++j) {
            float h = 0.f;
            #pragma unroll
            for (int d = 0; d < 8; ++d) h += v[d] * w0[d * 8 + j];
            sa += h * a0[j];
            sb += h * a0[8 + j];
        }
        pernode[n] = sa;
        pernode[2048 + n] = sb;
    }
    {
        float v[16];
        #pragma unroll
        for (int d = 0; d < 16; ++d) v[d] = st1[n * 16 + d];
        float sa = 0.f, sb = 0.f;
        #pragma unroll
        for (int j = 0; j < 16; ++j) {
            float h = 0.f;
            #pragma unroll
            for (int d = 0; d < 16; ++d) h += v[d] * w1[d * 16 + j];
            sa += h * a1[j];
            sb += h * a1[16 + j];
        }
        pernode[4096 + n] = sa;
        pernode[6144 + n] = sb;
    }
}

// ---------------- prep: bf16 weights (LSTM + proj + gating transposes) ----------------
__global__ void prep_kernel(const float* __restrict__ Wih, const float* __restrict__ Whh,
                            const float* __restrict__ bih, const float* __restrict__ bhh,
                            const float* __restrict__ Wl,
                            const float* __restrict__ dw1_0, const float* __restrict__ dw1_1,
                            const float* __restrict__ dw1_2,
                            const float* __restrict__ dw2_0, const float* __restrict__ dw2_1,
                            const float* __restrict__ dw2_2,
                            ushort_t* __restrict__ wihbf, ushort_t* __restrict__ whhbf,
                            float* __restrict__ bsum, ushort_t* __restrict__ wlTbf,
                            ushort_t* __restrict__ w1tb, ushort_t* __restrict__ w2tb)
{
    int idx = blockIdx.x * blockDim.x + threadIdx.x;
    if (idx < 32768) { wihbf[idx] = f2bf(Wih[idx]); return; }
    idx -= 32768;
    if (idx < 65536) { whhbf[idx] = f2bf(Whh[idx]); return; }
    idx -= 65536;
    if (idx < 512) { bsum[idx] = bih[idx] + bhh[idx]; return; }
    idx -= 512;
    if (idx < 16384) {
        int j = idx >> 7, hh = idx & 127;
        wlTbf[idx] = f2bf(Wl[hh * 128 + j]);   // WlT[j][h] = Wl[h][j]
        return;
    }
    idx -= 16384;
    if (idx < 12288) {
        // w1t: [cat][128 n][32 k] = W1_cat[k][n], zero-padded past d
        int c = idx >> 12;
        int r = idx & 4095;
        int n = r >> 5, k = r & 31;
        const float* W1 = (c == 0) ? dw1_0 : ((c == 1) ? dw1_1 : dw1_2);
        int d = (c == 1) ? 32 : 16;
        w1tb[idx >= 0 ? (c * 4096 + r) : 0] = (k < d) ? f2bf(W1[k * 128 + n]) : (ushort_t)0;
        return;
    }
    idx -= 12288;
    if (idx < 8192) {
        // w2t: cat0 [0,2048) d=16, cat1 [2048,6144) d=32, cat2 [6144,8192) d=16
        int c, base, d;
        if (idx < 2048)      { c = 0; base = 0;    d = 16; }
        else if (idx < 6144) { c = 1; base = 2048; d = 32; }
        else                 { c = 2; base = 6144; d = 16; }
        int r = idx - base;
        int n = r >> 7, k = r & 127;
        const float* W2 = (c == 0) ? dw2_0 : ((c == 1) ? dw2_1 : dw2_2);
        w2tb[idx] = f2bf(W2[k * d + n]);
    }
}

// ---------------- score rows + softmax + identity -> bf16 A ----------------
__global__ __launch_bounds__(256) void score_softmax_kernel(const float* __restrict__ dist,
                                                            const float* __restrict__ pernode,
                                                            ushort_t* __restrict__ Abf)
{
    __shared__ float srow[N_NODES];
    __shared__ float red[256];
    int n = blockIdx.x;
    int tid = threadIdx.x;
    float wd0 = pernode[8192], wd1 = pernode[8193], wd2 = pernode[8194], wd3 = pernode[8195];
    float s0 = pernode[n];
    float s1 = pernode[4096 + n];
    const float* s0m = pernode + 2048;
    const float* s1m = pernode + 6144;
    float mx = -1e30f;
    for (int m = tid; m < N_NODES; m += 256) {
        float4 dv = *reinterpret_cast<const float4*>(dist + ((size_t)n * N_NODES + m) * 4);
        float sc = sigmoidf_(s0 + s0m[m]) + sigmoidf_(s1 + s1m[m])
                 + sigmoidf_(dv.x * wd0 + dv.y * wd1 + dv.z * wd2 + dv.w * wd3);
        srow[m] = sc;
        mx = fmaxf(mx, sc);
    }
    red[tid] = mx;
    __syncthreads();
    for (int off = 128; off > 0; off >>= 1) {
        if (tid < off) red[tid] = fmaxf(red[tid], red[tid + off]);
        __syncthreads();
    }
    mx = red[0];
    __syncthreads();
    float sum = 0.f;
    for (int m = tid; m < N_NODES; m += 256) {
        float e = expf(srow[m] - mx);
        srow[m] = e;
        sum += e;
    }
    red[tid] = sum;
    __syncthreads();
    for (int off = 128; off > 0; off >>= 1) {
        if (tid < off) red[tid] += red[tid + off];
        __syncthreads();
    }
    float inv = 1.f / red[0];
    for (int m = tid; m < KP; m += 256) {
        float v = 0.f;
        if (m < N_NODES) v = srow[m] * inv + (m == n ? 1.f : 0.f);  // fold identity
        Abf[(size_t)n * KP + m] = f2bf(v);
    }
}

// ---------------- zero pad rows 2000..2047 of A ----------------
__global__ void padA_kernel(ushort_t* __restrict__ Abf)
{
    uint_t* p = (uint_t*)(Abf + (size_t)N_NODES * KP);
    int idx = blockIdx.x * blockDim.x + threadIdx.x;   // 192*256 = 49152 = 48*2048/2
    p[idx] = 0;
}

// ---------------- gating MLP via MFMA ----------------
// Per wave: 16 rows. L1: Z1 = dyn @ W1 + b1 (K=32, d-padded), lrelu -> bf16 ->
// per-wave XOR-swizzled LDS tile [16][128]. L2: out = A2 @ W2 + b2 (K=128),
// epilogue sigmoid(out) * dyn -> xout bf16.
template <int D, int XOFF>
__device__ __forceinline__ void gate_mfma_cat(
    const float* __restrict__ dyn, const float* __restrict__ b1,
    const float* __restrict__ b2,
    const ushort_t* __restrict__ w1t, const ushort_t* __restrict__ w2t,
    ushort_t* __restrict__ a2, ushort_t* __restrict__ xout, int r0, int lane)
{
    int col = lane & 15, rgrp = lane >> 4, ke = rgrp * 8;

    // A-frag (K=32, zero-padded beyond D)
    bf16x8 af = {};
    if (D == 32 || rgrp < 2) {
        const float* src = dyn + (size_t)(r0 + col) * D + ke;
        float4 va = *reinterpret_cast<const float4*>(src);
        float4 vb = *reinterpret_cast<const float4*>(src + 4);
        af[0] = (short)f2bf(va.x); af[1] = (short)f2bf(va.y);
        af[2] = (short)f2bf(va.z); af[3] = (short)f2bf(va.w);
        af[4] = (short)f2bf(vb.x); af[5] = (short)f2bf(vb.y);
        af[6] = (short)f2bf(vb.z); af[7] = (short)f2bf(vb.w);
    }

    __syncthreads();   // previous cat's L2 reads of a2 complete before overwrite
    #pragma unroll
    for (int mi = 0; mi < 8; ++mi) {
        bf16x8 bf = *(const bf16x8*)&w1t[(mi * 16 + col) * 32 + ke];
        float b1v = b1[mi * 16 + col];
        f32x4 acc = {b1v, b1v, b1v, b1v};
        acc = __builtin_amdgcn_mfma_f32_16x16x32_bf16(af, bf, acc, 0, 0, 0);
        #pragma unroll
        for (int jj = 0; jj < 4; ++jj) {
            int r = rgrp * 4 + jj;           // C row = (lane>>4)*4 + reg [m89]
            int j = mi * 16 + col;           // C col = lane&15
            a2[r * 128 + (((j >> 3) ^ (r & 7)) << 3) + (j & 7)] = f2bf(lrelu_(acc[jj]));
        }
    }
    __syncthreads();   // a2 writes visible / ordered before reads

    bf16x8 a2f[4];
    #pragma unroll
    for (int kt = 0; kt < 4; ++kt)
        a2f[kt] = *(const bf16x8*)&a2[col * 128 + (((kt * 4 + rgrp) ^ (col & 7)) << 3)];
    #pragma unroll
    for (int nt = 0; nt < D / 16; ++nt) {
        float b2v = b2[nt * 16 + col];
        f32x4 acc = {b2v, b2v, b2v, b2v};
        #pragma unroll
        for (int kt = 0; kt < 4; ++kt) {
            bf16x8 wf = *(const bf16x8*)&w2t[(nt * 16 + col) * 128 + kt * 32 + ke];
            acc = __builtin_amdgcn_mfma_f32_16x16x32_bf16(a2f[kt], wf, acc, 0, 0, 0);
        }
        #pragma unroll
        for (int jj = 0; jj < 4; ++jj) {
            int rg = r0 + rgrp * 4 + jj;
            int dd = nt * 16 + col;
            float xv = fast_sig(acc[jj]) * dyn[(size_t)rg * D + dd];
            xout[(size_t)rg * 64 + XOFF + dd] = f2bf(xv);
        }
    }
}

__global__ __launch_bounds__(256) void gating_mfma_kernel(
    const float* __restrict__ dyn0, const float* __restrict__ dyn1,
    const float* __restrict__ dyn2,
    const float* __restrict__ db1_0, const float* __restrict__ db1_1,
    const float* __restrict__ db1_2,
    const float* __restrict__ db2_0, const float* __restrict__ db2_1,
    const float* __restrict__ db2_2,
    const ushort_t* __restrict__ w1tb, const ushort_t* __restrict__ w2tb,
    ushort_t* __restrict__ xout)
{
    __shared__ ushort_t a2_lds[4][16 * 128];   // per-wave private tiles
    int tid  = threadIdx.x;
    int lane = tid & 63;
    int w    = tid >> 6;
    int r0   = blockIdx.x * 64 + w * 16;
    ushort_t* a2 = a2_lds[w];
    gate_mfma_cat<16, 0 >(dyn0, db1_0, db2_0, w1tb,        w2tb,        a2, xout, r0, lane);
    gate_mfma_cat<32, 16>(dyn1, db1_1, db2_1, w1tb + 4096, w2tb + 2048, a2, xout, r0, lane);
    gate_mfma_cat<16, 48>(dyn2, db1_2, db2_2, w1tb + 8192, w2tb + 6144, a2, xout, r0, lane);
}

// ---------------- LSTM via MFMA: 8 samples/block, 512 threads (8 waves) ----------------
// launch_bounds(512,2): VGPR cap 256 so the 24 persistent weight B-frags (96
// VGPR) stay register-resident (r8's 88-VGPR cap forced per-step reloads).
__global__ __launch_bounds__(512, 2) void lstm_mfma_kernel(
    const ushort_t* __restrict__ xbf,   // (N*T, 64) bf16, row r = n*64+t
    const ushort_t* __restrict__ wihbf, // (512, 64) bf16  [n][k]
    const ushort_t* __restrict__ whhbf, // (512, 128) bf16 [n][k]
    const float*    __restrict__ bsum,  // (512) bih+bhh
    ushort_t*       __restrict__ h_bf)  // (N, T*H) bf16
{
    __shared__ ushort_t xb_lds[2 * 512];   // double-buffered x_t: [8 samples][64], chunk-swizzled
    __shared__ ushort_t h_lds[16 * 128];   // [16 rows(8 pad)][128] bf16, chunk-swizzled

    int tid  = threadIdx.x;
    int lane = tid & 63;
    int w    = tid >> 6;          // wave 0..7
    int n0   = blockIdx.x * 8;
    int uc   = w * 16;            // unit chunk base
    int col  = lane & 15;         // C col / B n-offset
    int ke   = (lane >> 4) * 8;   // k-element base within 32-k tile
    int arow = lane & 15;         // A row for fragment reads
    int rgrp = lane >> 4;         // 0..3; C rows rgrp*4+j

    // prologue: stage x[t=0] into buffer 0. Global chunk pre-swizzled by sample
    // so LDS slot (s,c) holds logical chunk c^s (LDS dest stays linear).
    if (w == 0) {
        int s = lane >> 3, c = lane & 7;
        stage16(xbf + ((size_t)(n0 + s) * 64 + 0) * 64 + ((c ^ s) * 8), &xb_lds[0]);
    }

    // zero h (h0 = 0; rows 8..15 stay zero forever)
    ((uint_t*)h_lds)[tid] = 0;
    ((uint_t*)h_lds)[512 + tid] = 0;

    // B fragments + biases (persistent across t-loop)
    bf16x8 bihf[4][2];
    bf16x8 bhhf[4][4];
    float  bias[4];
    #pragma unroll
    for (int gi = 0; gi < 4; ++gi) {
        int n = gi * 128 + uc + col;
        bias[gi] = bsum[n];
        #pragma unroll
        for (int kt = 0; kt < 2; ++kt)
            bihf[gi][kt] = *(const bf16x8*)&wihbf[n * 64 + kt * 32 + ke];
        #pragma unroll
        for (int kt = 0; kt < 4; ++kt)
            bhhf[gi][kt] = *(const bf16x8*)&whhbf[n * 128 + kt * 32 + ke];
    }

    float c_st[4] = {0.f, 0.f, 0.f, 0.f};
    __syncthreads();   // x[0] staged (vmcnt drained), h zeros visible

    for (int t = 0; t < T_STEPS; ++t) {
        // ---- A fragments (swizzled reads) ----
        const ushort_t* xb = &xb_lds[(t & 1) * 512];
        bf16x8 ax[2] = {};
        if (arow < 8) {
            ax[0] = *(const bf16x8*)&xb[arow * 64 + ((rgrp ^ arow) << 3)];
            ax[1] = *(const bf16x8*)&xb[arow * 64 + (((4 + rgrp) ^ arow) << 3)];
        }
        bf16x8 ah[4];
        #pragma unroll
        for (int kt = 0; kt < 4; ++kt)
            ah[kt] = *(const bf16x8*)&h_lds[arow * 128 + (((kt * 4 + rgrp) ^ (arow & 7)) << 3)];
        __syncthreads();   // all reads done before any h writes this step

        // prefetch next x tile (latency hides under MFMA+gates; drained at end barrier)
        if (w == 0 && t + 1 < T_STEPS) {
            int s = lane >> 3, c = lane & 7;
            stage16(xbf + ((size_t)(n0 + s) * 64 + (t + 1)) * 64 + ((c ^ s) * 8),
                    &xb_lds[((t + 1) & 1) * 512]);
        }

        // ---- MFMA: acc[gi] = bias + x@Wih^T + h@Whh^T ----
        f32x4 acc[4];
        #pragma unroll
        for (int gi = 0; gi < 4; ++gi)
            acc[gi] = (f32x4){bias[gi], bias[gi], bias[gi], bias[gi]};
        #pragma unroll
        for (int gi = 0; gi < 4; ++gi) {
            #pragma unroll
            for (int kt = 0; kt < 2; ++kt)
                acc[gi] = __builtin_amdgcn_mfma_f32_16x16x32_bf16(ax[kt], bihf[gi][kt], acc[gi], 0, 0, 0);
            #pragma unroll
            for (int kt = 0; kt < 4; ++kt)
                acc[gi] = __builtin_amdgcn_mfma_f32_16x16x32_bf16(ah[kt], bhhf[gi][kt], acc[gi], 0, 0, 0);
        }

        // ---- gates in-register: C row = rgrp*4+j = sample (valid < 8) ----
        if (rgrp < 2) {
            int u = uc + col;
            int uch = u >> 3, ulo = u & 7;
            #pragma unroll
            for (int j = 0; j < 4; ++j) {
                float iv = fast_sig(acc[0][j]);
                float fv = fast_sig(acc[1][j]);
                float gv = fast_tanh(acc[2][j]);
                float ov = fast_sig(acc[3][j]);
                c_st[j] = fv * c_st[j] + iv * gv;
                float hv = ov * fast_tanh(c_st[j]);
                int s = rgrp * 4 + j;
                ushort_t hbv = f2bf(hv);
                h_lds[s * 128 + ((uch ^ s) << 3) + ulo] = hbv;
                h_bf[(size_t)(n0 + s) * NCOLS + t * H_DIM + u] = hbv;
            }
        }
        __syncthreads();   // h writes (+ wave0 prefetch vmcnt) complete
    }
}

// ---------------- transpose h (2000 x 8192 bf16) -> hT (8192 x 2048 bf16) ----------------
__global__ __launch_bounds__(256) void transposeH_kernel(const ushort_t* __restrict__ h_bf,
                                                         ushort_t* __restrict__ hT)
{
    __shared__ ushort_t tile[64][72];
    int c0 = blockIdx.x * 64;   // column of h / row of hT   (0..8191)
    int k0 = blockIdx.y * 64;   // row (node) of h / col of hT (0..2047)
    int tid = threadIdx.x;
    int rr = tid >> 4;          // 0..15
    int cc = (tid & 15) * 4;    // 0..60
    #pragma unroll
    for (int i = 0; i < 4; ++i) {
        int r = rr + i * 16;    // 0..63
        ushort_t v0 = 0, v1 = 0, v2 = 0, v3 = 0;
        if (k0 + r < N_NODES) {
            const ushort_t* src = h_bf + (size_t)(k0 + r) * NCOLS + c0 + cc;
            ushort4 v = *reinterpret_cast<const ushort4*>(src);
            v0 = v.x; v1 = v.y; v2 = v.z; v3 = v.w;
        }
        tile[r][cc] = v0; tile[r][cc + 1] = v1; tile[r][cc + 2] = v2; tile[r][cc + 3] = v3;
    }
    __syncthreads();
    #pragma unroll
    for (int i = 0; i < 4; ++i) {
        int r = rr + i * 16;    // row of hT tile (c-dim), 0..63
        ushort4 v;
        v.x = tile[cc][r]; v.y = tile[cc + 1][r]; v.z = tile[cc + 2][r]; v.w = tile[cc + 3][r];
        *reinterpret_cast<ushort4*>(hT + (size_t)(c0 + r) * KP + k0 + cc) = v;
    }
}

// ---------------- spatial aggregation via MFMA: C = (I+dis) @ h -> bf16 ----------------
// A: Abf [2048 x 2048] bf16 row-major, B: hT [8192 x 2048] bf16 (col-major of h),
// C: bf16 [2000 x 8192].  m97 structure: BM=BN=128, BK=32, 4 waves, 16x16x32 MFMA.
__global__ __launch_bounds__(256) void agg_gemm_mfma(const ushort_t* __restrict__ Abf,
                                                     const ushort_t* __restrict__ hT,
                                                     ushort_t* __restrict__ Cbf)
{
    __shared__ ushort_t A_lds[128 * 32];
    __shared__ ushort_t B_lds[128 * 32];
    int tid = threadIdx.x;
    int lane = tid & 63;
    int w = tid >> 6;          // wave 0..3
    int wr = w >> 1, wc = w & 1;
    int row0 = blockIdx.y * 128;
    int col0 = blockIdx.x * 128;

    f32x4 acc[4][4] = {};

    int lrow = lane >> 2;            // 0..15 (row-within-16 for staging)
    int lkk = (lane & 3) * 8;        // bf16 elements within 32-k row

    for (int k0 = 0; k0 < KP; k0 += 32) {
        // stage A tile: rows row0..row0+127, k k0..k0+31
        stage16(Abf + (size_t)(row0 + w * 16 + lrow) * KP + k0 + lkk,       &A_lds[w * 512]);
        stage16(Abf + (size_t)(row0 + 64 + w * 16 + lrow) * KP + k0 + lkk,  &A_lds[w * 512 + 2048]);
        // stage B tile: cols col0..col0+127 (rows of hT), same k range
        stage16(hT + (size_t)(col0 + w * 16 + lrow) * KP + k0 + lkk,        &B_lds[w * 512]);
        stage16(hT + (size_t)(col0 + 64 + w * 16 + lrow) * KP + k0 + lkk,   &B_lds[w * 512 + 2048]);
        __syncthreads();

        bf16x8 av[4], bv[4];
        #pragma unroll
        for (int mi = 0; mi < 4; ++mi)
            av[mi] = *(const bf16x8*)&A_lds[(wr * 64 + mi * 16 + (lane & 15)) * 32 + (lane >> 4) * 8];
        #pragma unroll
        for (int ni = 0; ni < 4; ++ni)
            bv[ni] = *(const bf16x8*)&B_lds[(wc * 64 + ni * 16 + (lane & 15)) * 32 + (lane >> 4) * 8];
        #pragma unroll
        for (int mi = 0; mi < 4; ++mi)
            #pragma unroll
            for (int ni = 0; ni < 4; ++ni)
                acc[mi][ni] = __builtin_amdgcn_mfma_f32_16x16x32_bf16(av[mi], bv[ni], acc[mi][ni], 0, 0, 0);
        __syncthreads();
    }

    // epilogue: D row = (lane>>4)*4 + reg, col = lane&15  [m89-verified]; emit bf16
    #pragma unroll
    for (int mi = 0; mi < 4; ++mi) {
        #pragma unroll
        for (int ni = 0; ni < 4; ++ni) {
            int colg = col0 + wc * 64 + ni * 16 + (lane & 15);
            #pragma unroll
            for (int j = 0; j < 4; ++j) {
                int rowg = row0 + wr * 64 + mi * 16 + (lane >> 4) * 4 + j;
                if (rowg < N_NODES)
                    Cbf[(size_t)rowg * NCOLS + colg] = f2bf(acc[mi][ni][j]);
            }
        }
    }
}

// ---------------- final projection via MFMA (operand-swapped, no LDS) ----------------
// Z^T[j][r] = sum_h WlT[j][h] * agg[r][h];  y[r] = sum_j lrelu(Z[j]+bl[j])*Wl2[j] + bl2
// Block: 256 thr / 4 waves; wave handles 32 agg rows (2 N-tiles); M = j = 8 tiles; K = h = 4 tiles.
__global__ __launch_bounds__(256) void final_proj_mfma(
    const ushort_t* __restrict__ aggbf,  // (128000, 128) bf16
    const ushort_t* __restrict__ wlTbf,  // (128, 128) bf16  [j][h]
    const float* __restrict__ bl,        // (128)
    const float* __restrict__ Wl2,       // (128)
    const float* __restrict__ bl2,       // (1)
    float* __restrict__ y)               // (128000)
{
    int tid  = threadIdx.x;
    int lane = tid & 63;
    int w    = tid >> 6;                    // 0..3
    int row0 = blockIdx.x * 128 + w * 32;   // this wave's 32 agg rows
    int col  = lane & 15;
    int rgrp = lane >> 4;                   // 0..3
    int ke   = rgrp * 8;

    // B fragments: agg rows (N dim), 2 n-tiles x 4 k-tiles, direct from global
    bf16x8 bfr[2][4];
    #pragma unroll
    for (int nt = 0; nt < 2; ++nt) {
        const ushort_t* base = aggbf + (size_t)(row0 + nt * 16 + col) * H_DIM;
        #pragma unroll
        for (int kt = 0; kt < 4; ++kt)
            bfr[nt][kt] = *(const bf16x8*)&base[kt * 32 + ke];
    }

    float yp0 = 0.f, yp1 = 0.f;
    #pragma unroll
    for (int mi = 0; mi < 8; ++mi) {
        bf16x8 af[4];
        const ushort_t* abase = wlTbf + (size_t)(mi * 16 + col) * H_DIM;
        #pragma unroll
        for (int kt = 0; kt < 4; ++kt)
            af[kt] = *(const bf16x8*)&abase[kt * 32 + ke];
        float4 blv = *reinterpret_cast<const float4*>(&bl[mi * 16 + rgrp * 4]);
        float4 w2v = *reinterpret_cast<const float4*>(&Wl2[mi * 16 + rgrp * 4]);
        f32x4 acc0 = {blv.x, blv.y, blv.z, blv.w};
        f32x4 acc1 = acc0;
        #pragma unroll
        for (int kt = 0; kt < 4; ++kt) {
            acc0 = __builtin_amdgcn_mfma_f32_16x16x32_bf16(af[kt], bfr[0][kt], acc0, 0, 0, 0);
            acc1 = __builtin_amdgcn_mfma_f32_16x16x32_bf16(af[kt], bfr[1][kt], acc1, 0, 0, 0);
        }
        yp0 += lrelu_(acc0[0]) * w2v.x + lrelu_(acc0[1]) * w2v.y
             + lrelu_(acc0[2]) * w2v.z + lrelu_(acc0[3]) * w2v.w;
        yp1 += lrelu_(acc1[0]) * w2v.x + lrelu_(acc1[1]) * w2v.y
             + lrelu_(acc1[2]) * w2v.z + lrelu_(acc1[3]) * w2v.w;
    }
    // reduce over the 4 rgrp groups (j-rows): lanes differing in bits 4,5
    yp0 += __shfl_xor(yp0, 16); yp0 += __shfl_xor(yp0, 32);
    yp1 += __shfl_xor(yp1, 16); yp1 += __shfl_xor(yp1, 32);
    if (lane < 16) {
        float b2 = bl2[0];
        y[row0 + col] = yp0 + b2;
        y[row0 + 16 + col] = yp1 + b2;
    }
}

extern "C" void kernel_launch(void* const* d_in, const int* in_sizes, int n_in,
                              void* d_out, int out_size, void* d_ws, size_t ws_size,
                              hipStream_t stream)
{
    const float* dyn0  = (const float*)d_in[0];
    const float* dw1_0 = (const float*)d_in[1];
    const float* db1_0 = (const float*)d_in[2];
    const float* dw2_0 = (const float*)d_in[3];
    const float* db2_0 = (const float*)d_in[4];
    const float* dyn1  = (const float*)d_in[5];
    const float* dw1_1 = (const float*)d_in[6];
    const float* db1_1 = (const float*)d_in[7];
    const float* dw2_1 = (const float*)d_in[8];
    const float* db2_1 = (const float*)d_in[9];
    const float* dyn2  = (const float*)d_in[10];
    const float* dw1_2 = (const float*)d_in[11];
    const float* db1_2 = (const float*)d_in[12];
    const float* dw2_2 = (const float*)d_in[13];
    const float* db2_2 = (const float*)d_in[14];
    const float* st0   = (const float*)d_in[15];
    const float* w_0   = (const float*)d_in[16];
    const float* a_0   = (const float*)d_in[17];
    const float* st1   = (const float*)d_in[18];
    const float* w_1   = (const float*)d_in[19];
    const float* a_1   = (const float*)d_in[20];
    const float* dist  = (const float*)d_in[21];
    const float* W_dis = (const float*)d_in[22];
    const float* a_dis = (const float*)d_in[23];
    const float* Wih   = (const float*)d_in[24];
    const float* Whh   = (const float*)d_in[25];
    const float* bih   = (const float*)d_in[26];
    const float* bhh   = (const float*)d_in[27];
    const float* Wl    = (const float*)d_in[28];
    const float* bl    = (const float*)d_in[29];
    const float* Wl2   = (const float*)d_in[30];
    const float* bl2   = (const float*)d_in[31];

    char* ws = (char*)d_ws;
    float*    pernode = (float*)ws;                      // @0          65,536 B
    float*    bsum    = (float*)(ws + 65536);            //              2,048 B
    ushort_t* wihbf   = (ushort_t*)(ws + 67584);         //             65,536 B
    ushort_t* whhbf   = (ushort_t*)(ws + 133120);        //            131,072 B
    ushort_t* wlTbf   = (ushort_t*)(ws + 264192);        //             32,768 B
    ushort_t* Abf     = (ushort_t*)(ws + 296960);        //          8,388,608 B (2048x2048)
    ushort_t* xbf     = (ushort_t*)(ws + 8685568);       //         16,384,000 B (128000x64)
    ushort_t* hbf     = (ushort_t*)(ws + 25069568);      //         32,768,000 B (2000x8192)
    ushort_t* hT      = (ushort_t*)(ws + 57837568);      //         33,554,432 B (8192x2048)
    ushort_t* aggbf   = (ushort_t*)(ws + 91392000);      //         32,768,000 B (128000x128)
    ushort_t* w1tb    = (ushort_t*)(ws + 124160000);     //             24,576 B (3x128x32)
    ushort_t* w2tb    = (ushort_t*)(ws + 124184576);     //             16,384 B (8192)
    // total 124,200,960 B

    hipLaunchKernelGGL(pernode_kernel, dim3(8), dim3(256), 0, stream,
                       st0, w_0, a_0, st1, w_1, a_1, W_dis, a_dis, pernode);
    hipLaunchKernelGGL(prep_kernel, dim3(530), dim3(256), 0, stream,
                       Wih, Whh, bih, bhh, Wl,
                       dw1_0, dw1_1, dw1_2, dw2_0, dw2_1, dw2_2,
                       wihbf, whhbf, bsum, wlTbf, w1tb, w2tb);
    hipLaunchKernelGGL(score_softmax_kernel, dim3(N_NODES), dim3(256), 0, stream,
                       dist, pernode, Abf);
    hipLaunchKernelGGL(padA_kernel, dim3(192), dim3(256), 0, stream, Abf);
    hipLaunchKernelGGL(gating_mfma_kernel, dim3(2000), dim3(256), 0, stream,
                       dyn0, dyn1, dyn2, db1_0, db1_1, db1_2,
                       db2_0, db2_1, db2_2, w1tb, w2tb, xbf);
    hipLaunchKernelGGL(lstm_mfma_kernel, dim3(N_NODES / 8), dim3(512), 0, stream,
                       xbf, wihbf, whhbf, bsum, hbf);
    hipLaunchKernelGGL(transposeH_kernel, dim3(NCOLS / 64, KP / 64), dim3(256), 0, stream,
                       hbf, hT);
    hipLaunchKernelGGL(agg_gemm_mfma, dim3(NCOLS / 128, KP / 128), dim3(256), 0, stream,
                       Abf, hT, aggbf);
    hipLaunchKernelGGL(final_proj_mfma, dim3(1000), dim3(256), 0, stream,
                       aggbf, wlTbf, bl, Wl2, bl2, (float*)d_out);
}